// Round 16
// baseline (13583.754 us; speedup 1.0000x reference)
//
#include <hip/hip_runtime.h>
#include <hip/hip_bf16.h>

#define BSZ 512
#define SEQ 64
#define IDIM 300
#define KP1 384           // input dim padded to multiple of 128
#define HDIM 1024
#define G4 4096
#define BH (BSZ*HDIM)     // 524288

typedef __attribute__((ext_vector_type(8))) short bf16x8;
typedef __attribute__((ext_vector_type(4))) float f32x4;
typedef __attribute__((ext_vector_type(8))) unsigned short u16x8;
typedef __attribute__((ext_vector_type(4))) unsigned short u16x4;

__device__ __forceinline__ float sigmoidf_(float x){ return 1.f/(1.f+__expf(-x)); }
__device__ __forceinline__ float bf2f(unsigned short u){
    union{unsigned int i; float f;} v; v.i = ((unsigned)u)<<16; return v.f;
}
__device__ __forceinline__ unsigned short f2bf(float f){
    __hip_bfloat16 b = __float2bfloat16(f);
    return *(unsigned short*)&b;
}

// ---------------- setup kernels ----------------
__global__ void embed_gather_k(const int* __restrict__ x, const float* __restrict__ embed,
                               __hip_bfloat16* __restrict__ xs){
    int t = blockIdx.x, b = blockIdx.y;
    int ix = x[b*SEQ + t];
    const float* src = embed + (size_t)ix * IDIM;
    __hip_bfloat16* dst = xs + ((size_t)t*BSZ + b) * KP1;
    for (int k = threadIdx.x; k < KP1; k += 64)
        dst[k] = __float2bfloat16(k < IDIM ? src[k] : 0.f);
}

// Repack weights to bf16, gate-interleaved rows:
// new row nr -> orig row ((nr>>5)&3)*1024 + (nr>>7)*32 + (nr&31)
__global__ void conv_w_k(const float* __restrict__ Wih_e, const float* __restrict__ Wih_d,
                         const float* __restrict__ Whh_e, const float* __restrict__ Whh_d,
                         __hip_bfloat16* __restrict__ Pe, __hip_bfloat16* __restrict__ Pd,
                         __hip_bfloat16* __restrict__ He, __hip_bfloat16* __restrict__ Hd){
    int nr = blockIdx.x, v = blockIdx.y;
    int orig = ((nr>>5)&3)*HDIM + (nr>>7)*32 + (nr&31);
    if (v < 2){
        const float* src = (v ? Wih_d : Wih_e) + (size_t)orig*IDIM;
        __hip_bfloat16* dst = (v ? Pd : Pe) + (size_t)nr*KP1;
        for (int k = threadIdx.x; k < KP1; k += 64)
            dst[k] = __float2bfloat16(k < IDIM ? src[k] : 0.f);
    } else {
        const float* src = ((v == 3) ? Whh_d : Whh_e) + (size_t)orig*HDIM;
        __hip_bfloat16* dst = ((v == 3) ? Hd : He) + (size_t)nr*HDIM;
        for (int k = threadIdx.x; k < HDIM; k += 64)
            dst[k] = __float2bfloat16(src[k]);
    }
}

__global__ void bias_comb_k(const float* __restrict__ a, const float* __restrict__ b2,
                            const float* __restrict__ c2, const float* __restrict__ d2,
                            float* __restrict__ be, float* __restrict__ bd){
    int i = blockIdx.x*256 + threadIdx.x;       // 8192
    int nr = i & 4095;
    int orig = ((nr>>5)&3)*HDIM + (nr>>7)*32 + (nr&31);
    if (i < G4) be[nr] = a[orig] + b2[orig];
    else        bd[nr] = c2[orig] + d2[orig];
}

__global__ void zero_hc_k(float* __restrict__ h, float* __restrict__ c,
                          __hip_bfloat16* __restrict__ h_bf,
                          unsigned int* __restrict__ bar, unsigned int* __restrict__ gen){
    int idx = blockIdx.x*256 + threadIdx.x;
    h[idx] = 0.f; c[idx] = 0.f; h_bf[idx] = __float2bfloat16(0.f);
    if (idx == 0){ bar[0] = 0u; gen[0] = 0u; }
}

#define BM 64
#define BN 128
#define NK1 (KP1/128)     // 3
#define NK2 (HDIM/128)    // 8
#define NKT (NK1+NK2)     // 11

// ---------------- grid barrier: relaxed-RMW poll, ONE fence per side ----------------
// Release: __threadfence() before arrival flushes this block's writes.
// Arrival/poll: RELAXED atomics only (execute at coherence point, no L2 invalidate).
// Acquire: single __threadfence() after the generation flips.
__device__ __forceinline__ void grid_sync_(unsigned int* bar, unsigned int* gen){
    __syncthreads();
    __threadfence();                             // release: flush our writes
    if (threadIdx.x == 0){
        unsigned int g = __hip_atomic_fetch_add(gen, 0u, __ATOMIC_RELAXED, __HIP_MEMORY_SCOPE_AGENT);
        if (__hip_atomic_fetch_add(bar, 1u, __ATOMIC_RELAXED, __HIP_MEMORY_SCOPE_AGENT) == 255u){
            __hip_atomic_store(bar, 0u, __ATOMIC_RELAXED, __HIP_MEMORY_SCOPE_AGENT);
            __hip_atomic_fetch_add(gen, 1u, __ATOMIC_RELEASE, __HIP_MEMORY_SCOPE_AGENT);
        } else {
            while (__hip_atomic_fetch_add(gen, 0u, __ATOMIC_RELAXED, __HIP_MEMORY_SCOPE_AGENT) == g)
                __builtin_amdgcn_s_sleep(16);
        }
    }
    __syncthreads();
    __threadfence();                             // acquire: invalidate once, see peers' writes
}

// ---------------- persistent encoder: 128 LSTM steps (fwd+bwd) in ONE dispatch ----------------
// 256 blocks x 512 thr, 96KB LDS -> exactly 1 block/CU. Math verbatim R9 lstm_step.
// c lives in registers across all 128 steps; h/c written to global once at the end.
__global__ __launch_bounds__(512) void enc_persist_k(
    const __hip_bfloat16* __restrict__ xs, const __hip_bfloat16* __restrict__ B1,
    const __hip_bfloat16* __restrict__ B2, const float* __restrict__ bias,
    float* __restrict__ c, float* __restrict__ h, __hip_bfloat16* __restrict__ h_bf,
    __hip_bfloat16* __restrict__ enc,
    unsigned int* __restrict__ bar, unsigned int* __restrict__ gen)
{
    __shared__ __align__(16) char smem[98304];
    const int tid  = threadIdx.x;
    const int lane = tid & 63, wv = tid >> 6;
    const int bid  = blockIdx.x;                 // 0..255
    const int bx = bid & 31, by = bid >> 5;
    const int row0 = by * BM;
    const int col0 = bx * BN;
    const int wm = wv >> 2, wn = wv & 3;

    const int erow = tid >> 3;
    const int ejj0 = (tid & 7) * 4;
    const size_t ebase = (size_t)(row0 + erow)*HDIM + bx*32 + ejj0;

    f32x4 creg = {0.f, 0.f, 0.f, 0.f};

    for (int i = 0; i < 2*SEQ; ++i){
        const int t = (i < SEQ) ? i : (2*SEQ - 1 - i);   // bwd reuses fwd's xs[t]
        const __hip_bfloat16* A1 = xs + (size_t)t*BSZ*KP1;

        auto stage = [&](int ks, int p){
            const __hip_bfloat16* A; const __hip_bfloat16* B; int KA, k0;
            if (ks < NK1){ A = A1;   B = B1; KA = KP1;  k0 = ks*128; }
            else         { A = h_bf; B = B2; KA = HDIM; k0 = (ks-NK1)*128; }
            char* base = smem + p*49152;
            #pragma unroll
            for (int half = 0; half < 2; ++half){   // A tile: 1024 slots of 16B
                int u = half*512 + tid;
                int r = u >> 4, s = u & 15;
                int g = s ^ (r & 15);
                const __hip_bfloat16* src = A + (size_t)(row0 + r)*KA + k0 + g*8;
                char* dst = base + half*8192 + wv*1024;
                __builtin_amdgcn_global_load_lds(
                    (const __attribute__((address_space(1))) void*)src,
                    (__attribute__((address_space(3))) void*)dst, 16, 0, 0);
            }
            #pragma unroll
            for (int q = 0; q < 4; ++q){            // B tile: 2048 slots
                int u = q*512 + tid;
                int r = u >> 4, s = u & 15;
                int g = s ^ (r & 15);
                const __hip_bfloat16* src = B + (size_t)(col0 + r)*KA + k0 + g*8;
                char* dst = base + 16384 + q*8192 + wv*1024;
                __builtin_amdgcn_global_load_lds(
                    (const __attribute__((address_space(1))) void*)src,
                    (__attribute__((address_space(3))) void*)dst, 16, 0, 0);
            }
        };

        f32x4 acc[2][2] = {};

        stage(0, 0);
        __syncthreads();
        for (int ks = 0; ks < NKT; ++ks){
            int p = ks & 1;
            if (ks + 1 < NKT) stage(ks + 1, p ^ 1);
            {
                const char* Ab = smem + p*49152;
                const char* Bb = Ab + 16384;
                const int rr = lane & 15, g = lane >> 4;
                bf16x8 af[2][4], bfr[2][4];
                #pragma unroll
                for (int m = 0; m < 2; ++m){
                    int r = wm*32 + m*16 + rr;
                    #pragma unroll
                    for (int kk = 0; kk < 4; ++kk)
                        af[m][kk] = *(const bf16x8*)(Ab + r*256 + ((kk*4 + g) ^ (r & 15))*16);
                }
                #pragma unroll
                for (int n = 0; n < 2; ++n){
                    int r = wn*32 + n*16 + rr;
                    #pragma unroll
                    for (int kk = 0; kk < 4; ++kk)
                        bfr[n][kk] = *(const bf16x8*)(Bb + r*256 + ((kk*4 + g) ^ (r & 15))*16);
                }
                #pragma unroll
                for (int kk = 0; kk < 4; ++kk)
                    #pragma unroll
                    for (int m = 0; m < 2; ++m)
                        #pragma unroll
                        for (int n = 0; n < 2; ++n)
                            acc[m][n] = __builtin_amdgcn_mfma_f32_16x16x32_bf16(af[m][kk], bfr[n][kk], acc[m][n], 0, 0, 0);
            }
            __syncthreads();
        }

        // epilogue: exchange gates via LDS (overlays buffer 0), apply LSTM cell
        float* ep = (float*)smem;
        {
            const int rr = lane & 15, q4 = lane >> 4;
            #pragma unroll
            for (int m = 0; m < 2; ++m){
                int row = wm*32 + m*16 + q4*4;
                #pragma unroll
                for (int n = 0; n < 2; ++n){
                    int jj = n*16 + rr;
                    float bi = bias[col0 + wn*32 + jj];
                    #pragma unroll
                    for (int q = 0; q < 4; ++q)
                        ep[(wn*64 + row + q)*33 + jj] = acc[m][n][q] + bi;
                }
            }
        }
        __syncthreads();
        {
            f32x4 hv;
            #pragma unroll
            for (int e = 0; e < 4; ++e){
                float gi = ep[(0*64 + erow)*33 + ejj0 + e];
                float gf = ep[(1*64 + erow)*33 + ejj0 + e];
                float gg = ep[(2*64 + erow)*33 + ejj0 + e];
                float go = ep[(3*64 + erow)*33 + ejj0 + e];
                float cc = sigmoidf_(gf)*creg[e] + sigmoidf_(gi)*tanhf(gg);
                float hh = sigmoidf_(go)*tanhf(cc);
                creg[e] = cc; hv[e] = hh;
            }
            u16x4 hb;
            #pragma unroll
            for (int e = 0; e < 4; ++e) hb[e] = f2bf(hv[e]);
            *(u16x4*)(h_bf + ebase) = hb;
            if (i < SEQ){
                *(u16x4*)(enc + (size_t)i*BH + ebase) = hb;
            } else {
                __hip_bfloat16* eslot = enc + (size_t)(i - SEQ)*BH;
                u16x4 eo = *(const u16x4*)(eslot + ebase);
                u16x4 r;
                #pragma unroll
                for (int e = 0; e < 4; ++e) r[e] = f2bf(0.5f*(bf2f(eo[e]) + hv[e]));
                *(u16x4*)(eslot + ebase) = r;
            }
            if (i == 2*SEQ - 1){
                *(f32x4*)(c + ebase) = creg;
                *(f32x4*)(h + ebase) = hv;
            }
        }
        grid_sync_(bar, gen);
    }
}

// ---------------- fused bf16 MFMA GEMM + LSTM cell (decoder — champion R9) ----------------
__global__ __launch_bounds__(512) void lstm_step_k(
    const __hip_bfloat16* __restrict__ A1, const __hip_bfloat16* __restrict__ B1,
    const __hip_bfloat16* __restrict__ A2, const __hip_bfloat16* __restrict__ B2,
    const float* __restrict__ bias,
    float* __restrict__ c, float* __restrict__ h, __hip_bfloat16* __restrict__ h_bf,
    __hip_bfloat16* __restrict__ encSlot, int mode)
{
    __shared__ __align__(16) char smem[98304];
    const int tid  = threadIdx.x;
    const int lane = tid & 63, wv = tid >> 6;
    const int row0 = blockIdx.y * BM;
    const int col0 = blockIdx.x * BN;
    const int wm = wv >> 2, wn = wv & 3;

    f32x4 acc[2][2] = {};

    auto stage = [&](int ks, int p){
        const __hip_bfloat16* A; const __hip_bfloat16* B; int KA, k0;
        if (ks < NK1){ A = A1; B = B1; KA = KP1;  k0 = ks*128; }
        else         { A = A2; B = B2; KA = HDIM; k0 = (ks-NK1)*128; }
        char* base = smem + p*49152;
        #pragma unroll
        for (int half = 0; half < 2; ++half){
            int u = half*512 + tid;
            int r = u >> 4, s = u & 15;
            int g = s ^ (r & 15);
            const __hip_bfloat16* src = A + (size_t)(row0 + r)*KA + k0 + g*8;
            char* dst = base + half*8192 + wv*1024;
            __builtin_amdgcn_global_load_lds(
                (const __attribute__((address_space(1))) void*)src,
                (__attribute__((address_space(3))) void*)dst, 16, 0, 0);
        }
        #pragma unroll
        for (int q = 0; q < 4; ++q){
            int u = q*512 + tid;
            int r = u >> 4, s = u & 15;
            int g = s ^ (r & 15);
            const __hip_bfloat16* src = B + (size_t)(col0 + r)*KA + k0 + g*8;
            char* dst = base + 16384 + q*8192 + wv*1024;
            __builtin_amdgcn_global_load_lds(
                (const __attribute__((address_space(1))) void*)src,
                (__attribute__((address_space(3))) void*)dst, 16, 0, 0);
        }
    };

    auto compute = [&](int p){
        const char* Ab = smem + p*49152;
        const char* Bb = Ab + 16384;
        const int rr = lane & 15, g = lane >> 4;
        bf16x8 af[2][4], bfr[2][4];
        #pragma unroll
        for (int m = 0; m < 2; ++m){
            int r = wm*32 + m*16 + rr;
            #pragma unroll
            for (int kk = 0; kk < 4; ++kk)
                af[m][kk] = *(const bf16x8*)(Ab + r*256 + ((kk*4 + g) ^ (r & 15))*16);
        }
        #pragma unroll
        for (int n = 0; n < 2; ++n){
            int r = wn*32 + n*16 + rr;
            #pragma unroll
            for (int kk = 0; kk < 4; ++kk)
                bfr[n][kk] = *(const bf16x8*)(Bb + r*256 + ((kk*4 + g) ^ (r & 15))*16);
        }
        #pragma unroll
        for (int kk = 0; kk < 4; ++kk)
            #pragma unroll
            for (int m = 0; m < 2; ++m)
                #pragma unroll
                for (int n = 0; n < 2; ++n)
                    acc[m][n] = __builtin_amdgcn_mfma_f32_16x16x32_bf16(af[m][kk], bfr[n][kk], acc[m][n], 0, 0, 0);
    };

    const int erow = tid >> 3;
    const int ejj0 = (tid & 7) * 4;
    const size_t ebase = (size_t)(row0 + erow)*HDIM + blockIdx.x*32 + ejj0;

    stage(0, 0);
    const f32x4 cpre = *(const f32x4*)(c + ebase);
    __syncthreads();
    for (int ks = 0; ks < NKT; ++ks){
        int p = ks & 1;
        if (ks + 1 < NKT) stage(ks + 1, p ^ 1);
        compute(p);
        __syncthreads();
    }

    float* ep = (float*)smem;
    {
        const int rr = lane & 15, q4 = lane >> 4;
        #pragma unroll
        for (int m = 0; m < 2; ++m){
            int row = wm*32 + m*16 + q4*4;
            #pragma unroll
            for (int n = 0; n < 2; ++n){
                int jj = n*16 + rr;
                float bi = bias[col0 + wn*32 + jj];
                #pragma unroll
                for (int q = 0; q < 4; ++q)
                    ep[(wn*64 + row + q)*33 + jj] = acc[m][n][q] + bi;
            }
        }
    }
    __syncthreads();
    {
        f32x4 cv, hv;
        #pragma unroll
        for (int e = 0; e < 4; ++e){
            float gi = ep[(0*64 + erow)*33 + ejj0 + e];
            float gf = ep[(1*64 + erow)*33 + ejj0 + e];
            float gg = ep[(2*64 + erow)*33 + ejj0 + e];
            float go = ep[(3*64 + erow)*33 + ejj0 + e];
            float cc = sigmoidf_(gf)*cpre[e] + sigmoidf_(gi)*tanhf(gg);
            float hh = sigmoidf_(go)*tanhf(cc);
            cv[e] = cc; hv[e] = hh;
        }
        *(f32x4*)(c + ebase) = cv;
        *(f32x4*)(h + ebase) = hv;
        u16x4 hb;
        #pragma unroll
        for (int e = 0; e < 4; ++e) hb[e] = f2bf(hv[e]);
        *(u16x4*)(h_bf + ebase) = hb;
        if (mode == 0){
            *(u16x4*)(encSlot + ebase) = hb;
        } else if (mode == 1){
            u16x4 eo = *(const u16x4*)(encSlot + ebase);
            u16x4 r;
            #pragma unroll
            for (int e = 0; e < 4; ++e) r[e] = f2bf(0.5f*(bf2f(eo[e]) + hv[e]));
            *(u16x4*)(encSlot + ebase) = r;
        }
    }
}

// ---------------- attention logits (+ fused dec_linear of previous step) ----------------
// 1D grid of 640 blocks: bid<512 -> logits (ch = bid&63, 8 timesteps each, h reg-cached);
// bid>=512 -> dec_linear for step dect (4 batches/block).
__global__ __launch_bounds__(256) void attn_part_k(
    const __hip_bfloat16* __restrict__ h_bf, const __hip_bfloat16* __restrict__ enc,
    float* __restrict__ part,
    const float* __restrict__ h, const float* __restrict__ Wl, const float* __restrict__ bl,
    const int* __restrict__ len, float* __restrict__ out, int dect)
{
    int lane = threadIdx.x & 63, w = threadIdx.x >> 6;
    if (blockIdx.x < 512){
        int ch = blockIdx.x & 63;                // h/enc chunk of 8192 elems
        int s0 = (blockIdx.x >> 6) * 8;          // 8 timesteps per block
        const u16x8* hp = (const u16x8*)(h_bf + (size_t)ch*8192);
        float hf[4][8];
        #pragma unroll
        for (int k = 0; k < 4; ++k){
            u16x8 hv = hp[threadIdx.x + k*256];
            #pragma unroll
            for (int j = 0; j < 8; ++j) hf[k][j] = bf2f(hv[j]);
        }
        __shared__ float red[8][4];
        for (int si = 0; si < 8; ++si){
            const u16x8* e = (const u16x8*)(enc + (size_t)(s0 + si)*BH + (size_t)ch*8192);
            float sum = 0.f;
            #pragma unroll
            for (int k = 0; k < 4; ++k){
                u16x8 ev = e[threadIdx.x + k*256];
                #pragma unroll
                for (int j = 0; j < 8; ++j) sum += hf[k][j] * bf2f(ev[j]);
            }
            #pragma unroll
            for (int m = 32; m >= 1; m >>= 1) sum += __shfl_xor(sum, m);
            if (lane == 0) red[si][w] = sum;
        }
        __syncthreads();
        if (threadIdx.x < 8){
            int si = threadIdx.x;
            part[(s0 + si)*64 + ch] = red[si][0]+red[si][1]+red[si][2]+red[si][3];
        }
    } else if (dect >= 0){
        int b = (blockIdx.x - 512)*4 + w;       // [0,512)
        const float* hb = h + (size_t)b*HDIM;
        float s0 = 0.f, s1 = 0.f;
        for (int j = lane; j < HDIM; j += 64){
            float v = hb[j];
            s0 += v * Wl[j];
            s1 += v * Wl[HDIM + j];
        }
        #pragma unroll
        for (int m = 32; m >= 1; m >>= 1){ s0 += __shfl_xor(s0, m); s1 += __shfl_xor(s1, m); }
        if (lane == 0){
            bool valid = dect < len[b];
            size_t r = ((size_t)b*SEQ + dect)*2;
            out[r]   = valid ? (s0 + bl[0]) : 1.0f;
            out[r+1] = valid ? (s1 + bl[1]) : 0.0f;
        }
    }
}

// softmax fused; hat written as bf16 (decoder GEMM A2 input). 512 blocks, 4 elems/thread.
__global__ __launch_bounds__(256) void attn_apply_k(
    const float* __restrict__ h, const float* __restrict__ part,
    const __hip_bfloat16* __restrict__ enc, __hip_bfloat16* __restrict__ hat_bf)
{
    __shared__ float wl[64];
    int lane = threadIdx.x & 63;
    if (threadIdx.x < 64){
        float tot = 0.f;
        #pragma unroll 8
        for (int ch = 0; ch < 64; ++ch) tot += part[lane*64 + ch];
        float m = tot;
        #pragma unroll
        for (int msk = 32; msk >= 1; msk >>= 1) m = fmaxf(m, __shfl_xor(m, msk));
        float e = __expf(tot - m);
        float sm = e;
        #pragma unroll
        for (int msk = 32; msk >= 1; msk >>= 1) sm += __shfl_xor(sm, msk);
        wl[lane] = e / sm;
    }
    __syncthreads();
    size_t i4 = ((size_t)blockIdx.x*256 + threadIdx.x) * 4;
    float v[4];
    {
        f32x4 a = *(const f32x4*)(h + i4);
        v[0]=a[0]; v[1]=a[1]; v[2]=a[2]; v[3]=a[3];
    }
    for (int s = 0; s < SEQ; ++s){
        u16x4 ev = *(const u16x4*)(enc + (size_t)s*BH + i4);
        float w = wl[s];
        #pragma unroll
        for (int j = 0; j < 4; ++j) v[j] += w * bf2f(ev[j]);
    }
    u16x4 ov;
    #pragma unroll
    for (int j = 0; j < 4; ++j) ov[j] = f2bf(v[j]);
    *(u16x4*)(hat_bf + i4) = ov;
}

// ---------------- standalone final linear (last decoder step) ----------------
__global__ void dec_linear_k(const float* __restrict__ h, const float* __restrict__ Wl,
                             const float* __restrict__ bl, const int* __restrict__ len,
                             float* __restrict__ out, int t)
{
    int b = blockIdx.x, lane = threadIdx.x;
    const float* hb = h + (size_t)b*HDIM;
    float s0 = 0.f, s1 = 0.f;
    for (int j = lane; j < HDIM; j += 64){
        float v = hb[j];
        s0 += v * Wl[j];
        s1 += v * Wl[HDIM + j];
    }
    #pragma unroll
    for (int m = 32; m >= 1; m >>= 1){ s0 += __shfl_xor(s0, m); s1 += __shfl_xor(s1, m); }
    if (lane == 0){
        bool valid = t < len[b];
        size_t r = ((size_t)b*SEQ + t)*2;
        out[r]   = valid ? (s0 + bl[0]) : 1.0f;
        out[r+1] = valid ? (s1 + bl[1]) : 0.0f;
    }
}

// ---------------- launch ----------------
extern "C" void kernel_launch(void* const* d_in, const int* in_sizes, int n_in,
                              void* d_out, int out_size, void* d_ws, size_t ws_size,
                              hipStream_t stream)
{
    (void)in_sizes; (void)n_in; (void)out_size; (void)ws_size;
    const int*   x      = (const int*)  d_in[0];
    const int*   len    = (const int*)  d_in[1];
    const float* embed  = (const float*)d_in[2];
    const float* Wih_e  = (const float*)d_in[3];
    const float* Whh_e  = (const float*)d_in[4];
    const float* bih_e  = (const float*)d_in[5];
    const float* bhh_e  = (const float*)d_in[6];
    const float* Wih_d  = (const float*)d_in[7];
    const float* Whh_d  = (const float*)d_in[8];
    const float* bih_d  = (const float*)d_in[9];
    const float* bhh_d  = (const float*)d_in[10];
    const float* W_lin  = (const float*)d_in[11];
    const float* b_lin  = (const float*)d_in[12];
    float* out = (float*)d_out;

    float* ws = (float*)d_ws;
    size_t off = 0;
    auto alloc = [&](size_t nfloats){ size_t o = off; off += (nfloats + 63) & ~(size_t)63; return o; };
    __hip_bfloat16* xs_bf  = (__hip_bfloat16*)(ws + alloc((size_t)SEQ*BSZ*KP1/2));
    __hip_bfloat16* Pe     = (__hip_bfloat16*)(ws + alloc((size_t)G4*KP1/2));
    __hip_bfloat16* Pd     = (__hip_bfloat16*)(ws + alloc((size_t)G4*KP1/2));
    __hip_bfloat16* He     = (__hip_bfloat16*)(ws + alloc((size_t)G4*HDIM/2));
    __hip_bfloat16* Hd     = (__hip_bfloat16*)(ws + alloc((size_t)G4*HDIM/2));
    float* be   = ws + alloc(G4);
    float* bd   = ws + alloc(G4);
    float* h    = ws + alloc(BH);
    float* c    = ws + alloc(BH);
    __hip_bfloat16* h_bf   = (__hip_bfloat16*)(ws + alloc(BH/2));
    __hip_bfloat16* hat_bf = (__hip_bfloat16*)(ws + alloc(BH/2));
    __hip_bfloat16* enc    = (__hip_bfloat16*)(ws + alloc((size_t)SEQ*BH/2));  // 64 MB
    float* part = ws + alloc(64*64);
    unsigned int* bar = (unsigned int*)(ws + alloc(32));
    unsigned int* gen = bar + 16;               // separate cacheline

    embed_gather_k<<<dim3(SEQ, BSZ), 64, 0, stream>>>(x, embed, xs_bf);
    conv_w_k<<<dim3(G4, 4), 64, 0, stream>>>(Wih_e, Wih_d, Whh_e, Whh_d, Pe, Pd, He, Hd);
    bias_comb_k<<<32, 256, 0, stream>>>(bih_e, bhh_e, bih_d, bhh_d, be, bd);
    zero_hc_k<<<BH/256, 256, 0, stream>>>(h, c, h_bf, bar, gen);

    // whole encoder (fwd + bwd, 128 steps) in one persistent dispatch
    enc_persist_k<<<256, 512, 0, stream>>>(xs_bf, Pe, He, be, c, h, h_bf, enc, bar, gen);

    dim3 ggrid(G4/BN, BSZ/BM);   // (32, 8) = 256 blocks
    // decoder: attn_part(t) also carries dec_linear(t-1)
    for (int t = 0; t < SEQ; ++t){
        attn_part_k<<<640, 256, 0, stream>>>(h_bf, enc, part, h, W_lin, b_lin, len, out, t - 1);
        attn_apply_k<<<512, 256, 0, stream>>>(h, part, enc, hat_bf);
        lstm_step_k<<<ggrid, 512, 0, stream>>>(xs_bf + (size_t)t*BSZ*KP1, Pd, hat_bf, Hd, bd,
                                               c, h, h_bf, nullptr, 2);
    }
    dec_linear_k<<<BSZ, 64, 0, stream>>>(h, W_lin, b_lin, len, out, SEQ - 1);
}

// Round 17
// 5920.729 us; speedup vs baseline: 2.2943x; 2.2943x over previous
//
#include <hip/hip_runtime.h>
#include <hip/hip_bf16.h>

#define BSZ 512
#define SEQ 64
#define IDIM 300
#define KP1 384           // input dim padded to multiple of 128
#define HDIM 1024
#define G4 4096
#define BH (BSZ*HDIM)     // 524288

typedef __attribute__((ext_vector_type(8))) short bf16x8;
typedef __attribute__((ext_vector_type(4))) float f32x4;
typedef __attribute__((ext_vector_type(8))) unsigned short u16x8;
typedef __attribute__((ext_vector_type(4))) unsigned short u16x4;

__device__ __forceinline__ float sigmoidf_(float x){ return 1.f/(1.f+__expf(-x)); }
__device__ __forceinline__ float bf2f(unsigned short u){
    union{unsigned int i; float f;} v; v.i = ((unsigned)u)<<16; return v.f;
}
__device__ __forceinline__ unsigned short f2bf(float f){
    __hip_bfloat16 b = __float2bfloat16(f);
    return *(unsigned short*)&b;
}

// ---------------- setup kernels ----------------
__global__ void embed_gather_k(const int* __restrict__ x, const float* __restrict__ embed,
                               __hip_bfloat16* __restrict__ xs){
    int t = blockIdx.x, b = blockIdx.y;
    int ix = x[b*SEQ + t];
    const float* src = embed + (size_t)ix * IDIM;
    __hip_bfloat16* dst = xs + ((size_t)t*BSZ + b) * KP1;
    for (int k = threadIdx.x; k < KP1; k += 64)
        dst[k] = __float2bfloat16(k < IDIM ? src[k] : 0.f);
}

// Repack weights to bf16, gate-interleaved rows:
// new row nr -> orig row ((nr>>5)&3)*1024 + (nr>>7)*32 + (nr&31)
__global__ void conv_w_k(const float* __restrict__ Wih_e, const float* __restrict__ Wih_d,
                         const float* __restrict__ Whh_e, const float* __restrict__ Whh_d,
                         __hip_bfloat16* __restrict__ Pe, __hip_bfloat16* __restrict__ Pd,
                         __hip_bfloat16* __restrict__ He, __hip_bfloat16* __restrict__ Hd){
    int nr = blockIdx.x, v = blockIdx.y;
    int orig = ((nr>>5)&3)*HDIM + (nr>>7)*32 + (nr&31);
    if (v < 2){
        const float* src = (v ? Wih_d : Wih_e) + (size_t)orig*IDIM;
        __hip_bfloat16* dst = (v ? Pd : Pe) + (size_t)nr*KP1;
        for (int k = threadIdx.x; k < KP1; k += 64)
            dst[k] = __float2bfloat16(k < IDIM ? src[k] : 0.f);
    } else {
        const float* src = ((v == 3) ? Whh_d : Whh_e) + (size_t)orig*HDIM;
        __hip_bfloat16* dst = ((v == 3) ? Hd : He) + (size_t)nr*HDIM;
        for (int k = threadIdx.x; k < HDIM; k += 64)
            dst[k] = __float2bfloat16(src[k]);
    }
}

__global__ void bias_comb_k(const float* __restrict__ a, const float* __restrict__ b2,
                            const float* __restrict__ c2, const float* __restrict__ d2,
                            float* __restrict__ be, float* __restrict__ bd){
    int i = blockIdx.x*256 + threadIdx.x;       // 8192
    int nr = i & 4095;
    int orig = ((nr>>5)&3)*HDIM + (nr>>7)*32 + (nr&31);
    if (i < G4) be[nr] = a[orig] + b2[orig];
    else        bd[nr] = c2[orig] + d2[orig];
}

__global__ void zero_hc_k(float* __restrict__ h, float* __restrict__ c,
                          __hip_bfloat16* __restrict__ h_bf){
    int idx = blockIdx.x*256 + threadIdx.x;
    h[idx] = 0.f; c[idx] = 0.f; h_bf[idx] = __float2bfloat16(0.f);
}

#define BM 64
#define BN 128
#define NK1 (KP1/128)     // 3
#define NK2 (HDIM/128)    // 8
#define NKT (NK1+NK2)     // 11

// ---------------- fused bf16 MFMA GEMM + LSTM cell (+ optional next-step logits) ----------------
__global__ __launch_bounds__(512) void lstm_step_k(
    const __hip_bfloat16* __restrict__ A1, const __hip_bfloat16* __restrict__ B1,
    const __hip_bfloat16* __restrict__ A2, const __hip_bfloat16* __restrict__ B2,
    const float* __restrict__ bias,
    float* __restrict__ c, float* __restrict__ h, __hip_bfloat16* __restrict__ h_bf,
    __hip_bfloat16* __restrict__ encSlot, int mode,
    const __hip_bfloat16* __restrict__ enc_all, float* __restrict__ part, int logits)
{
    __shared__ __align__(16) char smem[98304];
    const int tid  = threadIdx.x;
    const int lane = tid & 63, wv = tid >> 6;
    const int row0 = blockIdx.y * BM;
    const int col0 = blockIdx.x * BN;
    const int wm = wv >> 2, wn = wv & 3;

    f32x4 acc[2][2] = {};

    auto stage = [&](int ks, int p){
        const __hip_bfloat16* A; const __hip_bfloat16* B; int KA, k0;
        if (ks < NK1){ A = A1; B = B1; KA = KP1;  k0 = ks*128; }
        else         { A = A2; B = B2; KA = HDIM; k0 = (ks-NK1)*128; }
        char* base = smem + p*49152;
        #pragma unroll
        for (int half = 0; half < 2; ++half){   // A tile: 1024 slots of 16B, 2 per thread
            int u = half*512 + tid;
            int r = u >> 4, s = u & 15;
            int g = s ^ (r & 15);               // inverse swizzle on global source
            const __hip_bfloat16* src = A + (size_t)(row0 + r)*KA + k0 + g*8;
            char* dst = base + half*8192 + wv*1024;
            __builtin_amdgcn_global_load_lds(
                (const __attribute__((address_space(1))) void*)src,
                (__attribute__((address_space(3))) void*)dst, 16, 0, 0);
        }
        #pragma unroll
        for (int q = 0; q < 4; ++q){            // B tile: 2048 slots, 4 per thread
            int u = q*512 + tid;
            int r = u >> 4, s = u & 15;
            int g = s ^ (r & 15);
            const __hip_bfloat16* src = B + (size_t)(col0 + r)*KA + k0 + g*8;
            char* dst = base + 16384 + q*8192 + wv*1024;
            __builtin_amdgcn_global_load_lds(
                (const __attribute__((address_space(1))) void*)src,
                (__attribute__((address_space(3))) void*)dst, 16, 0, 0);
        }
    };

    auto compute = [&](int p){
        const char* Ab = smem + p*49152;
        const char* Bb = Ab + 16384;
        const int rr = lane & 15, g = lane >> 4;
        bf16x8 af[2][4], bfr[2][4];
        #pragma unroll
        for (int m = 0; m < 2; ++m){
            int r = wm*32 + m*16 + rr;
            #pragma unroll
            for (int kk = 0; kk < 4; ++kk)
                af[m][kk] = *(const bf16x8*)(Ab + r*256 + ((kk*4 + g) ^ (r & 15))*16);
        }
        #pragma unroll
        for (int n = 0; n < 2; ++n){
            int r = wn*32 + n*16 + rr;
            #pragma unroll
            for (int kk = 0; kk < 4; ++kk)
                bfr[n][kk] = *(const bf16x8*)(Bb + r*256 + ((kk*4 + g) ^ (r & 15))*16);
        }
        #pragma unroll
        for (int kk = 0; kk < 4; ++kk)
            #pragma unroll
            for (int m = 0; m < 2; ++m)
                #pragma unroll
                for (int n = 0; n < 2; ++n)
                    acc[m][n] = __builtin_amdgcn_mfma_f32_16x16x32_bf16(af[m][kk], bfr[n][kk], acc[m][n], 0, 0, 0);
    };

    // epilogue indices + c prefetch (latency hides under the K loop)
    const int erow = tid >> 3;
    const int ejj0 = (tid & 7) * 4;
    const size_t ebase = (size_t)(row0 + erow)*HDIM + blockIdx.x*32 + ejj0;

    stage(0, 0);
    const f32x4 cpre = *(const f32x4*)(c + ebase);
    __syncthreads();
    for (int ks = 0; ks < NKT; ++ks){
        int p = ks & 1;
        if (ks + 1 < NKT) stage(ks + 1, p ^ 1);
        compute(p);
        __syncthreads();
    }

    // ---- epilogue: exchange gates via LDS, apply LSTM cell ----
    float* ep = (float*)smem;                    // [gate][64][33] floats
    {
        const int rr = lane & 15, q4 = lane >> 4;
        #pragma unroll
        for (int m = 0; m < 2; ++m){
            int row = wm*32 + m*16 + q4*4;
            #pragma unroll
            for (int n = 0; n < 2; ++n){
                int jj = n*16 + rr;
                float bi = bias[col0 + wn*32 + jj];
                #pragma unroll
                for (int q = 0; q < 4; ++q)
                    ep[(wn*64 + row + q)*33 + jj] = acc[m][n][q] + bi;
            }
        }
    }
    __syncthreads();
    f32x4 hv;
    {
        f32x4 cv;
        #pragma unroll
        for (int e = 0; e < 4; ++e){
            float gi = ep[(0*64 + erow)*33 + ejj0 + e];
            float gf = ep[(1*64 + erow)*33 + ejj0 + e];
            float gg = ep[(2*64 + erow)*33 + ejj0 + e];
            float go = ep[(3*64 + erow)*33 + ejj0 + e];
            float cc = sigmoidf_(gf)*cpre[e] + sigmoidf_(gi)*tanhf(gg);
            float hh = sigmoidf_(go)*tanhf(cc);
            cv[e] = cc; hv[e] = hh;
        }
        *(f32x4*)(c + ebase) = cv;
        *(f32x4*)(h + ebase) = hv;
        u16x4 hb;
        #pragma unroll
        for (int e = 0; e < 4; ++e) hb[e] = f2bf(hv[e]);
        *(u16x4*)(h_bf + ebase) = hb;
        if (mode == 0){
            *(u16x4*)(encSlot + ebase) = hb;
        } else if (mode == 1){
            u16x4 eo = *(const u16x4*)(encSlot + ebase);
            u16x4 r;
            #pragma unroll
            for (int e = 0; e < 4; ++e) r[e] = f2bf(0.5f*(bf2f(eo[e]) + hv[e]));
            *(u16x4*)(encSlot + ebase) = r;
        }
    }

    // ---- optional: partial attention logits for the NEXT decoder step ----
    // logit[s] partial over this block's (64-batch x 32-hidden) h slice (in regs).
    if (logits){
        __syncthreads();                        // ep reads done; reuse smem
        float* lp = (float*)smem;               // [64 s][8 waves]
        for (int s = 0; s < SEQ; ++s){
            u16x4 ev = *(const u16x4*)(enc_all + (size_t)s*BH + ebase);
            float p = hv[0]*bf2f(ev[0]) + hv[1]*bf2f(ev[1])
                    + hv[2]*bf2f(ev[2]) + hv[3]*bf2f(ev[3]);
            #pragma unroll
            for (int m = 32; m >= 1; m >>= 1) p += __shfl_xor(p, m);
            if (lane == 0) lp[s*8 + wv] = p;
        }
        __syncthreads();
        if (tid < SEQ){
            float t8 = 0.f;
            #pragma unroll
            for (int w8 = 0; w8 < 8; ++w8) t8 += lp[tid*8 + w8];
            part[tid*256 + (blockIdx.y*32 + blockIdx.x)] = t8;
        }
    }
}

// ---------------- initial attention logits (t=0, from encoder-final h_bf) ----------------
// 512 blocks: ch = bid&63 (8192-elem chunk), 8 timesteps each; writes part[s*64+ch].
__global__ __launch_bounds__(256) void attn_part_k(
    const __hip_bfloat16* __restrict__ h_bf, const __hip_bfloat16* __restrict__ enc,
    float* __restrict__ part)
{
    int lane = threadIdx.x & 63, w = threadIdx.x >> 6;
    int ch = blockIdx.x & 63;
    int s0 = (blockIdx.x >> 6) * 8;
    const u16x8* hp = (const u16x8*)(h_bf + (size_t)ch*8192);
    float hf[4][8];
    #pragma unroll
    for (int k = 0; k < 4; ++k){
        u16x8 hv = hp[threadIdx.x + k*256];
        #pragma unroll
        for (int j = 0; j < 8; ++j) hf[k][j] = bf2f(hv[j]);
    }
    __shared__ float red[8][4];
    for (int si = 0; si < 8; ++si){
        const u16x8* e = (const u16x8*)(enc + (size_t)(s0 + si)*BH + (size_t)ch*8192);
        float sum = 0.f;
        #pragma unroll
        for (int k = 0; k < 4; ++k){
            u16x8 ev = e[threadIdx.x + k*256];
            #pragma unroll
            for (int j = 0; j < 8; ++j) sum += hf[k][j] * bf2f(ev[j]);
        }
        #pragma unroll
        for (int m = 32; m >= 1; m >>= 1) sum += __shfl_xor(sum, m);
        if (lane == 0) red[si][w] = sum;
    }
    __syncthreads();
    if (threadIdx.x < 8){
        int si = threadIdx.x;
        part[(s0 + si)*64 + ch] = red[si][0]+red[si][1]+red[si][2]+red[si][3];
    }
}

// ---------------- softmax + weighted sum (+ fused dec_linear of previous step) ----------------
// blocks <512: hat; blocks >=512: dec_linear for step dect (4 batches/block).
__global__ __launch_bounds__(256) void attn_apply_k(
    const float* __restrict__ h, const float* __restrict__ part, int nPart,
    const __hip_bfloat16* __restrict__ enc, __hip_bfloat16* __restrict__ hat_bf,
    const float* __restrict__ Wl, const float* __restrict__ bl,
    const int* __restrict__ len, float* __restrict__ out, int dect)
{
    int lane = threadIdx.x & 63, w = threadIdx.x >> 6;
    if (blockIdx.x < 512){
        __shared__ float wl[64];
        if (threadIdx.x < 64){
            float tot = 0.f;
            #pragma unroll 8
            for (int k = 0; k < nPart; ++k) tot += part[lane*nPart + k];
            float m = tot;
            #pragma unroll
            for (int msk = 32; msk >= 1; msk >>= 1) m = fmaxf(m, __shfl_xor(m, msk));
            float e = __expf(tot - m);
            float sm = e;
            #pragma unroll
            for (int msk = 32; msk >= 1; msk >>= 1) sm += __shfl_xor(sm, msk);
            wl[lane] = e / sm;
        }
        __syncthreads();
        size_t i4 = ((size_t)blockIdx.x*256 + threadIdx.x) * 4;
        float v[4];
        {
            f32x4 a = *(const f32x4*)(h + i4);
            v[0]=a[0]; v[1]=a[1]; v[2]=a[2]; v[3]=a[3];
        }
        for (int s = 0; s < SEQ; ++s){
            u16x4 ev = *(const u16x4*)(enc + (size_t)s*BH + i4);
            float ww = wl[s];
            #pragma unroll
            for (int j = 0; j < 4; ++j) v[j] += ww * bf2f(ev[j]);
        }
        u16x4 ov;
        #pragma unroll
        for (int j = 0; j < 4; ++j) ov[j] = f2bf(v[j]);
        *(u16x4*)(hat_bf + i4) = ov;
    } else if (dect >= 0){
        int b = (blockIdx.x - 512)*4 + w;       // [0,512)
        const float* hb = h + (size_t)b*HDIM;
        float s0 = 0.f, s1 = 0.f;
        for (int j = lane; j < HDIM; j += 64){
            float v = hb[j];
            s0 += v * Wl[j];
            s1 += v * Wl[HDIM + j];
        }
        #pragma unroll
        for (int m = 32; m >= 1; m >>= 1){ s0 += __shfl_xor(s0, m); s1 += __shfl_xor(s1, m); }
        if (lane == 0){
            bool valid = dect < len[b];
            size_t r = ((size_t)b*SEQ + dect)*2;
            out[r]   = valid ? (s0 + bl[0]) : 1.0f;
            out[r+1] = valid ? (s1 + bl[1]) : 0.0f;
        }
    }
}

// ---------------- standalone final linear (last decoder step) ----------------
__global__ void dec_linear_k(const float* __restrict__ h, const float* __restrict__ Wl,
                             const float* __restrict__ bl, const int* __restrict__ len,
                             float* __restrict__ out, int t)
{
    int b = blockIdx.x, lane = threadIdx.x;
    const float* hb = h + (size_t)b*HDIM;
    float s0 = 0.f, s1 = 0.f;
    for (int j = lane; j < HDIM; j += 64){
        float v = hb[j];
        s0 += v * Wl[j];
        s1 += v * Wl[HDIM + j];
    }
    #pragma unroll
    for (int m = 32; m >= 1; m >>= 1){ s0 += __shfl_xor(s0, m); s1 += __shfl_xor(s1, m); }
    if (lane == 0){
        bool valid = t < len[b];
        size_t r = ((size_t)b*SEQ + t)*2;
        out[r]   = valid ? (s0 + bl[0]) : 1.0f;
        out[r+1] = valid ? (s1 + bl[1]) : 0.0f;
    }
}

// ---------------- launch ----------------
extern "C" void kernel_launch(void* const* d_in, const int* in_sizes, int n_in,
                              void* d_out, int out_size, void* d_ws, size_t ws_size,
                              hipStream_t stream)
{
    (void)in_sizes; (void)n_in; (void)out_size; (void)ws_size;
    const int*   x      = (const int*)  d_in[0];
    const int*   len    = (const int*)  d_in[1];
    const float* embed  = (const float*)d_in[2];
    const float* Wih_e  = (const float*)d_in[3];
    const float* Whh_e  = (const float*)d_in[4];
    const float* bih_e  = (const float*)d_in[5];
    const float* bhh_e  = (const float*)d_in[6];
    const float* Wih_d  = (const float*)d_in[7];
    const float* Whh_d  = (const float*)d_in[8];
    const float* bih_d  = (const float*)d_in[9];
    const float* bhh_d  = (const float*)d_in[10];
    const float* W_lin  = (const float*)d_in[11];
    const float* b_lin  = (const float*)d_in[12];
    float* out = (float*)d_out;

    float* ws = (float*)d_ws;
    size_t off = 0;
    auto alloc = [&](size_t nfloats){ size_t o = off; off += (nfloats + 63) & ~(size_t)63; return o; };
    __hip_bfloat16* xs_bf  = (__hip_bfloat16*)(ws + alloc((size_t)SEQ*BSZ*KP1/2));
    __hip_bfloat16* Pe     = (__hip_bfloat16*)(ws + alloc((size_t)G4*KP1/2));
    __hip_bfloat16* Pd     = (__hip_bfloat16*)(ws + alloc((size_t)G4*KP1/2));
    __hip_bfloat16* He     = (__hip_bfloat16*)(ws + alloc((size_t)G4*HDIM/2));
    __hip_bfloat16* Hd     = (__hip_bfloat16*)(ws + alloc((size_t)G4*HDIM/2));
    float* be   = ws + alloc(G4);
    float* bd   = ws + alloc(G4);
    float* h    = ws + alloc(BH);
    float* c    = ws + alloc(BH);
    __hip_bfloat16* h_bf   = (__hip_bfloat16*)(ws + alloc(BH/2));
    __hip_bfloat16* hat_bf = (__hip_bfloat16*)(ws + alloc(BH/2));
    __hip_bfloat16* enc    = (__hip_bfloat16*)(ws + alloc((size_t)SEQ*BH/2));  // 64 MB
    float* part = ws + alloc(64*256);

    embed_gather_k<<<dim3(SEQ, BSZ), 64, 0, stream>>>(x, embed, xs_bf);
    conv_w_k<<<dim3(G4, 4), 64, 0, stream>>>(Wih_e, Wih_d, Whh_e, Whh_d, Pe, Pd, He, Hd);
    bias_comb_k<<<32, 256, 0, stream>>>(bih_e, bhh_e, bih_d, bhh_d, be, bd);
    zero_hc_k<<<BH/256, 256, 0, stream>>>(h, c, h_bf);

    dim3 ggrid(G4/BN, BSZ/BM);   // (32, 8) = 256 blocks

    // encoder forward
    for (int t = 0; t < SEQ; ++t)
        lstm_step_k<<<ggrid, 512, 0, stream>>>(xs_bf + (size_t)t*BSZ*KP1, Pe, h_bf, He, be,
                                               c, h, h_bf, enc + (size_t)t*BH, 0,
                                               nullptr, nullptr, 0);
    // encoder backward (carry continues); combine in place
    for (int k = 0; k < SEQ; ++k){
        int t = SEQ - 1 - k;
        lstm_step_k<<<ggrid, 512, 0, stream>>>(xs_bf + (size_t)t*BSZ*KP1, Pe, h_bf, He, be,
                                               c, h, h_bf, enc + (size_t)k*BH, 1,
                                               nullptr, nullptr, 0);
    }
    // initial logits for decoder step 0 (layout [s][64])
    attn_part_k<<<512, 256, 0, stream>>>(h_bf, enc, part);
    // decoder: apply(t) [+dec_linear(t-1)] -> lstm(t) [+logits(t+1)]
    for (int t = 0; t < SEQ; ++t){
        attn_apply_k<<<640, 256, 0, stream>>>(h, part, (t == 0) ? 64 : 256, enc, hat_bf,
                                              W_lin, b_lin, len, out, t - 1);
        lstm_step_k<<<ggrid, 512, 0, stream>>>(xs_bf + (size_t)t*BSZ*KP1, Pd, hat_bf, Hd, bd,
                                               c, h, h_bf, nullptr, 2,
                                               enc, part, (t < SEQ - 1) ? 1 : 0);
    }
    dec_linear_k<<<BSZ, 64, 0, stream>>>(h, W_lin, b_lin, len, out, SEQ - 1);
}

// Round 18
// 4123.697 us; speedup vs baseline: 3.2941x; 1.4358x over previous
//
#include <hip/hip_runtime.h>
#include <hip/hip_bf16.h>

#define BSZ 512
#define SEQ 64
#define IDIM 300
#define KP1 384           // input dim padded to multiple of 128
#define HDIM 1024
#define G4 4096
#define BH (BSZ*HDIM)     // 524288

typedef __attribute__((ext_vector_type(8))) short bf16x8;
typedef __attribute__((ext_vector_type(4))) float f32x4;
typedef __attribute__((ext_vector_type(8))) unsigned short u16x8;
typedef __attribute__((ext_vector_type(4))) unsigned short u16x4;

__device__ __forceinline__ float sigmoidf_(float x){ return 1.f/(1.f+__expf(-x)); }
__device__ __forceinline__ float bf2f(unsigned short u){
    union{unsigned int i; float f;} v; v.i = ((unsigned)u)<<16; return v.f;
}
__device__ __forceinline__ unsigned short f2bf(float f){
    __hip_bfloat16 b = __float2bfloat16(f);
    return *(unsigned short*)&b;
}

// ---------------- setup kernels ----------------
__global__ void embed_gather_k(const int* __restrict__ x, const float* __restrict__ embed,
                               __hip_bfloat16* __restrict__ xs){
    int t = blockIdx.x, b = blockIdx.y;
    int ix = x[b*SEQ + t];
    const float* src = embed + (size_t)ix * IDIM;
    __hip_bfloat16* dst = xs + ((size_t)t*BSZ + b) * KP1;
    for (int k = threadIdx.x; k < KP1; k += 64)
        dst[k] = __float2bfloat16(k < IDIM ? src[k] : 0.f);
}

// Repack weights to bf16, gate-interleaved rows:
// new row nr -> orig row ((nr>>5)&3)*1024 + (nr>>7)*32 + (nr&31)
__global__ void conv_w_k(const float* __restrict__ Wih_e, const float* __restrict__ Wih_d,
                         const float* __restrict__ Whh_e, const float* __restrict__ Whh_d,
                         __hip_bfloat16* __restrict__ Pe, __hip_bfloat16* __restrict__ Pd,
                         __hip_bfloat16* __restrict__ He, __hip_bfloat16* __restrict__ Hd){
    int nr = blockIdx.x, v = blockIdx.y;
    int orig = ((nr>>5)&3)*HDIM + (nr>>7)*32 + (nr&31);
    if (v < 2){
        const float* src = (v ? Wih_d : Wih_e) + (size_t)orig*IDIM;
        __hip_bfloat16* dst = (v ? Pd : Pe) + (size_t)nr*KP1;
        for (int k = threadIdx.x; k < KP1; k += 64)
            dst[k] = __float2bfloat16(k < IDIM ? src[k] : 0.f);
    } else {
        const float* src = ((v == 3) ? Whh_d : Whh_e) + (size_t)orig*HDIM;
        __hip_bfloat16* dst = ((v == 3) ? Hd : He) + (size_t)nr*HDIM;
        for (int k = threadIdx.x; k < HDIM; k += 64)
            dst[k] = __float2bfloat16(src[k]);
    }
}

__global__ void bias_comb_k(const float* __restrict__ a, const float* __restrict__ b2,
                            const float* __restrict__ c2, const float* __restrict__ d2,
                            float* __restrict__ be, float* __restrict__ bd){
    int i = blockIdx.x*256 + threadIdx.x;       // 8192
    int nr = i & 4095;
    int orig = ((nr>>5)&3)*HDIM + (nr>>7)*32 + (nr&31);
    if (i < G4) be[nr] = a[orig] + b2[orig];
    else        bd[nr] = c2[orig] + d2[orig];
}

__global__ void zero_hc_k(float* __restrict__ h, float* __restrict__ c,
                          __hip_bfloat16* __restrict__ h_bf){
    int idx = blockIdx.x*256 + threadIdx.x;
    h[idx] = 0.f; c[idx] = 0.f; h_bf[idx] = __float2bfloat16(0.f);
}

#define BM 64
#define BN 128
#define NK1 (KP1/128)     // 3
#define NK2 (HDIM/128)    // 8
#define NKT (NK1+NK2)     // 11

// ---------------- fused bf16 MFMA GEMM + LSTM cell (BK=128, 8 waves — champion R9/R15) ----------------
// mode 0: enc fwd (skip h-f32 store)   mode 1: enc bwd combine (skip h-f32 store)
// mode 3: enc bwd LAST step (combine + write h f32)   mode 2: decoder (write h f32)
__global__ __launch_bounds__(512) void lstm_step_k(
    const __hip_bfloat16* __restrict__ A1, const __hip_bfloat16* __restrict__ B1,
    const __hip_bfloat16* __restrict__ A2, const __hip_bfloat16* __restrict__ B2,
    const float* __restrict__ bias,
    float* __restrict__ c, float* __restrict__ h, __hip_bfloat16* __restrict__ h_bf,
    __hip_bfloat16* __restrict__ encSlot, int mode)
{
    // per buffer: A 64r x 256B = 16KB, B 128r x 256B = 32KB; 2 buffers = 96KB.
    __shared__ __align__(16) char smem[98304];
    const int tid  = threadIdx.x;
    const int lane = tid & 63, wv = tid >> 6;
    const int row0 = blockIdx.y * BM;
    const int col0 = blockIdx.x * BN;
    const int wm = wv >> 2, wn = wv & 3;

    f32x4 acc[2][2] = {};

    auto stage = [&](int ks, int p){
        const __hip_bfloat16* A; const __hip_bfloat16* B; int KA, k0;
        if (ks < NK1){ A = A1; B = B1; KA = KP1;  k0 = ks*128; }
        else         { A = A2; B = B2; KA = HDIM; k0 = (ks-NK1)*128; }
        char* base = smem + p*49152;
        #pragma unroll
        for (int half = 0; half < 2; ++half){   // A tile: 1024 slots of 16B, 2 per thread
            int u = half*512 + tid;
            int r = u >> 4, s = u & 15;
            int g = s ^ (r & 15);               // inverse swizzle on global source
            const __hip_bfloat16* src = A + (size_t)(row0 + r)*KA + k0 + g*8;
            char* dst = base + half*8192 + wv*1024;   // wave-uniform base; +lane*16 implicit
            __builtin_amdgcn_global_load_lds(
                (const __attribute__((address_space(1))) void*)src,
                (__attribute__((address_space(3))) void*)dst, 16, 0, 0);
        }
        #pragma unroll
        for (int q = 0; q < 4; ++q){            // B tile: 2048 slots, 4 per thread
            int u = q*512 + tid;
            int r = u >> 4, s = u & 15;
            int g = s ^ (r & 15);
            const __hip_bfloat16* src = B + (size_t)(col0 + r)*KA + k0 + g*8;
            char* dst = base + 16384 + q*8192 + wv*1024;
            __builtin_amdgcn_global_load_lds(
                (const __attribute__((address_space(1))) void*)src,
                (__attribute__((address_space(3))) void*)dst, 16, 0, 0);
        }
    };

    auto compute = [&](int p){
        const char* Ab = smem + p*49152;
        const char* Bb = Ab + 16384;
        const int rr = lane & 15, g = lane >> 4;
        bf16x8 af[2][4], bfr[2][4];
        #pragma unroll
        for (int m = 0; m < 2; ++m){
            int r = wm*32 + m*16 + rr;
            #pragma unroll
            for (int kk = 0; kk < 4; ++kk)
                af[m][kk] = *(const bf16x8*)(Ab + r*256 + ((kk*4 + g) ^ (r & 15))*16);
        }
        #pragma unroll
        for (int n = 0; n < 2; ++n){
            int r = wn*32 + n*16 + rr;
            #pragma unroll
            for (int kk = 0; kk < 4; ++kk)
                bfr[n][kk] = *(const bf16x8*)(Bb + r*256 + ((kk*4 + g) ^ (r & 15))*16);
        }
        #pragma unroll
        for (int kk = 0; kk < 4; ++kk)
            #pragma unroll
            for (int m = 0; m < 2; ++m)
                #pragma unroll
                for (int n = 0; n < 2; ++n)
                    acc[m][n] = __builtin_amdgcn_mfma_f32_16x16x32_bf16(af[m][kk], bfr[n][kk], acc[m][n], 0, 0, 0);
    };

    // epilogue indices + c prefetch (latency hides under the K loop)
    const int erow = tid >> 3;
    const int ejj0 = (tid & 7) * 4;
    const size_t ebase = (size_t)(row0 + erow)*HDIM + blockIdx.x*32 + ejj0;

    stage(0, 0);
    const f32x4 cpre = *(const f32x4*)(c + ebase);
    __syncthreads();
    for (int ks = 0; ks < NKT; ++ks){
        int p = ks & 1;
        if (ks + 1 < NKT) stage(ks + 1, p ^ 1);
        compute(p);
        __syncthreads();
    }

    // ---- epilogue: exchange gates via LDS, apply LSTM cell ----
    float* ep = (float*)smem;                    // [gate][64][33] floats
    {
        const int rr = lane & 15, q4 = lane >> 4;
        #pragma unroll
        for (int m = 0; m < 2; ++m){
            int row = wm*32 + m*16 + q4*4;
            #pragma unroll
            for (int n = 0; n < 2; ++n){
                int jj = n*16 + rr;
                float bi = bias[col0 + wn*32 + jj];
                #pragma unroll
                for (int q = 0; q < 4; ++q)
                    ep[(wn*64 + row + q)*33 + jj] = acc[m][n][q] + bi;
            }
        }
    }
    __syncthreads();
    {
        f32x4 cv, hv;
        #pragma unroll
        for (int e = 0; e < 4; ++e){
            float gi = ep[(0*64 + erow)*33 + ejj0 + e];
            float gf = ep[(1*64 + erow)*33 + ejj0 + e];
            float gg = ep[(2*64 + erow)*33 + ejj0 + e];
            float go = ep[(3*64 + erow)*33 + ejj0 + e];
            float cc = sigmoidf_(gf)*cpre[e] + sigmoidf_(gi)*tanhf(gg);
            float hh = sigmoidf_(go)*tanhf(cc);
            cv[e] = cc; hv[e] = hh;
        }
        *(f32x4*)(c + ebase) = cv;
        if (mode >= 2)                           // h f32 live only for decoder / last-enc step
            *(f32x4*)(h + ebase) = hv;
        u16x4 hb;
        #pragma unroll
        for (int e = 0; e < 4; ++e) hb[e] = f2bf(hv[e]);
        *(u16x4*)(h_bf + ebase) = hb;
        if (mode == 0){
            *(u16x4*)(encSlot + ebase) = hb;
        } else if (mode == 1 || mode == 3){
            u16x4 eo = *(const u16x4*)(encSlot + ebase);
            u16x4 r;
            #pragma unroll
            for (int e = 0; e < 4; ++e) r[e] = f2bf(0.5f*(bf2f(eo[e]) + hv[e]));
            *(u16x4*)(encSlot + ebase) = r;
        }
    }
}

// ---------------- attention logits (+ fused dec_linear of previous step) ----------------
// 1D grid of 640 blocks: bid<512 -> logits (ch = bid&63, 8 timesteps each, h reg-cached);
// bid>=512 -> dec_linear for step dect (4 batches/block).
__global__ __launch_bounds__(256) void attn_part_k(
    const __hip_bfloat16* __restrict__ h_bf, const __hip_bfloat16* __restrict__ enc,
    float* __restrict__ part,
    const float* __restrict__ h, const float* __restrict__ Wl, const float* __restrict__ bl,
    const int* __restrict__ len, float* __restrict__ out, int dect)
{
    int lane = threadIdx.x & 63, w = threadIdx.x >> 6;
    if (blockIdx.x < 512){
        int ch = blockIdx.x & 63;                // h/enc chunk of 8192 elems
        int s0 = (blockIdx.x >> 6) * 8;          // 8 timesteps per block
        const u16x8* hp = (const u16x8*)(h_bf + (size_t)ch*8192);
        float hf[4][8];
        #pragma unroll
        for (int k = 0; k < 4; ++k){
            u16x8 hv = hp[threadIdx.x + k*256];
            #pragma unroll
            for (int j = 0; j < 8; ++j) hf[k][j] = bf2f(hv[j]);
        }
        __shared__ float red[8][4];
        for (int si = 0; si < 8; ++si){
            const u16x8* e = (const u16x8*)(enc + (size_t)(s0 + si)*BH + (size_t)ch*8192);
            float sum = 0.f;
            #pragma unroll
            for (int k = 0; k < 4; ++k){
                u16x8 ev = e[threadIdx.x + k*256];
                #pragma unroll
                for (int j = 0; j < 8; ++j) sum += hf[k][j] * bf2f(ev[j]);
            }
            #pragma unroll
            for (int m = 32; m >= 1; m >>= 1) sum += __shfl_xor(sum, m);
            if (lane == 0) red[si][w] = sum;
        }
        __syncthreads();
        if (threadIdx.x < 8){
            int si = threadIdx.x;
            part[(s0 + si)*64 + ch] = red[si][0]+red[si][1]+red[si][2]+red[si][3];
        }
    } else if (dect >= 0){
        int b = (blockIdx.x - 512)*4 + w;       // [0,512)
        const float* hb = h + (size_t)b*HDIM;
        float s0 = 0.f, s1 = 0.f;
        for (int j = lane; j < HDIM; j += 64){
            float v = hb[j];
            s0 += v * Wl[j];
            s1 += v * Wl[HDIM + j];
        }
        #pragma unroll
        for (int m = 32; m >= 1; m >>= 1){ s0 += __shfl_xor(s0, m); s1 += __shfl_xor(s1, m); }
        if (lane == 0){
            bool valid = dect < len[b];
            size_t r = ((size_t)b*SEQ + dect)*2;
            out[r]   = valid ? (s0 + bl[0]) : 1.0f;
            out[r+1] = valid ? (s1 + bl[1]) : 0.0f;
        }
    }
}

// softmax fused; hat written as bf16 (decoder GEMM A2 input). 512 blocks, 4 elems/thread.
__global__ __launch_bounds__(256) void attn_apply_k(
    const float* __restrict__ h, const float* __restrict__ part,
    const __hip_bfloat16* __restrict__ enc, __hip_bfloat16* __restrict__ hat_bf)
{
    __shared__ float wl[64];
    int lane = threadIdx.x & 63;
    if (threadIdx.x < 64){
        float tot = 0.f;
        #pragma unroll 8
        for (int ch = 0; ch < 64; ++ch) tot += part[lane*64 + ch];
        float m = tot;
        #pragma unroll
        for (int msk = 32; msk >= 1; msk >>= 1) m = fmaxf(m, __shfl_xor(m, msk));
        float e = __expf(tot - m);
        float sm = e;
        #pragma unroll
        for (int msk = 32; msk >= 1; msk >>= 1) sm += __shfl_xor(sm, msk);
        wl[lane] = e / sm;
    }
    __syncthreads();
    size_t i4 = ((size_t)blockIdx.x*256 + threadIdx.x) * 4;
    float v[4];
    {
        f32x4 a = *(const f32x4*)(h + i4);
        v[0]=a[0]; v[1]=a[1]; v[2]=a[2]; v[3]=a[3];
    }
    for (int s = 0; s < SEQ; ++s){
        u16x4 ev = *(const u16x4*)(enc + (size_t)s*BH + i4);
        float w = wl[s];
        #pragma unroll
        for (int j = 0; j < 4; ++j) v[j] += w * bf2f(ev[j]);
    }
    u16x4 ov;
    #pragma unroll
    for (int j = 0; j < 4; ++j) ov[j] = f2bf(v[j]);
    *(u16x4*)(hat_bf + i4) = ov;
}

// ---------------- standalone final linear (last decoder step) ----------------
__global__ void dec_linear_k(const float* __restrict__ h, const float* __restrict__ Wl,
                             const float* __restrict__ bl, const int* __restrict__ len,
                             float* __restrict__ out, int t)
{
    int b = blockIdx.x, lane = threadIdx.x;
    const float* hb = h + (size_t)b*HDIM;
    float s0 = 0.f, s1 = 0.f;
    for (int j = lane; j < HDIM; j += 64){
        float v = hb[j];
        s0 += v * Wl[j];
        s1 += v * Wl[HDIM + j];
    }
    #pragma unroll
    for (int m = 32; m >= 1; m >>= 1){ s0 += __shfl_xor(s0, m); s1 += __shfl_xor(s1, m); }
    if (lane == 0){
        bool valid = t < len[b];
        size_t r = ((size_t)b*SEQ + t)*2;
        out[r]   = valid ? (s0 + bl[0]) : 1.0f;
        out[r+1] = valid ? (s1 + bl[1]) : 0.0f;
    }
}

// ---------------- launch ----------------
extern "C" void kernel_launch(void* const* d_in, const int* in_sizes, int n_in,
                              void* d_out, int out_size, void* d_ws, size_t ws_size,
                              hipStream_t stream)
{
    (void)in_sizes; (void)n_in; (void)out_size; (void)ws_size;
    const int*   x      = (const int*)  d_in[0];
    const int*   len    = (const int*)  d_in[1];
    const float* embed  = (const float*)d_in[2];
    const float* Wih_e  = (const float*)d_in[3];
    const float* Whh_e  = (const float*)d_in[4];
    const float* bih_e  = (const float*)d_in[5];
    const float* bhh_e  = (const float*)d_in[6];
    const float* Wih_d  = (const float*)d_in[7];
    const float* Whh_d  = (const float*)d_in[8];
    const float* bih_d  = (const float*)d_in[9];
    const float* bhh_d  = (const float*)d_in[10];
    const float* W_lin  = (const float*)d_in[11];
    const float* b_lin  = (const float*)d_in[12];
    float* out = (float*)d_out;

    float* ws = (float*)d_ws;
    size_t off = 0;
    auto alloc = [&](size_t nfloats){ size_t o = off; off += (nfloats + 63) & ~(size_t)63; return o; };
    __hip_bfloat16* xs_bf  = (__hip_bfloat16*)(ws + alloc((size_t)SEQ*BSZ*KP1/2));
    __hip_bfloat16* Pe     = (__hip_bfloat16*)(ws + alloc((size_t)G4*KP1/2));
    __hip_bfloat16* Pd     = (__hip_bfloat16*)(ws + alloc((size_t)G4*KP1/2));
    __hip_bfloat16* He     = (__hip_bfloat16*)(ws + alloc((size_t)G4*HDIM/2));
    __hip_bfloat16* Hd     = (__hip_bfloat16*)(ws + alloc((size_t)G4*HDIM/2));
    float* be   = ws + alloc(G4);
    float* bd   = ws + alloc(G4);
    float* h    = ws + alloc(BH);
    float* c    = ws + alloc(BH);
    __hip_bfloat16* h_bf   = (__hip_bfloat16*)(ws + alloc(BH/2));
    __hip_bfloat16* hat_bf = (__hip_bfloat16*)(ws + alloc(BH/2));
    __hip_bfloat16* enc    = (__hip_bfloat16*)(ws + alloc((size_t)SEQ*BH/2));  // 64 MB
    float* part = ws + alloc(64*64);

    embed_gather_k<<<dim3(SEQ, BSZ), 64, 0, stream>>>(x, embed, xs_bf);
    conv_w_k<<<dim3(G4, 4), 64, 0, stream>>>(Wih_e, Wih_d, Whh_e, Whh_d, Pe, Pd, He, Hd);
    bias_comb_k<<<32, 256, 0, stream>>>(bih_e, bhh_e, bih_d, bhh_d, be, bd);
    zero_hc_k<<<BH/256, 256, 0, stream>>>(h, c, h_bf);

    dim3 ggrid(G4/BN, BSZ/BM);   // (32, 8) = 256 blocks

    // encoder forward (h f32 store skipped — dead)
    for (int t = 0; t < SEQ; ++t)
        lstm_step_k<<<ggrid, 512, 0, stream>>>(xs_bf + (size_t)t*BSZ*KP1, Pe, h_bf, He, be,
                                               c, h, h_bf, enc + (size_t)t*BH, 0);
    // encoder backward (carry continues); combine in place; last step writes h f32 (mode 3)
    for (int k = 0; k < SEQ; ++k){
        int t = SEQ - 1 - k;
        lstm_step_k<<<ggrid, 512, 0, stream>>>(xs_bf + (size_t)t*BSZ*KP1, Pe, h_bf, He, be,
                                               c, h, h_bf, enc + (size_t)k*BH,
                                               (k == SEQ - 1) ? 3 : 1);
    }
    // decoder: attn_part(t) also carries dec_linear(t-1)
    for (int t = 0; t < SEQ; ++t){
        attn_part_k<<<640, 256, 0, stream>>>(h_bf, enc, part, h, W_lin, b_lin, len, out, t - 1);
        attn_apply_k<<<512, 256, 0, stream>>>(h, part, enc, hat_bf);
        lstm_step_k<<<ggrid, 512, 0, stream>>>(xs_bf + (size_t)t*BSZ*KP1, Pd, hat_bf, Hd, bd,
                                               c, h, h_bf, nullptr, 2);
    }
    dec_linear_k<<<BSZ, 64, 0, stream>>>(h, W_lin, b_lin, len, out, SEQ - 1);
}

// Round 19
// 3628.081 us; speedup vs baseline: 3.7441x; 1.1366x over previous
//
#include <hip/hip_runtime.h>
#include <hip/hip_bf16.h>

#define BSZ 512
#define SEQ 64
#define IDIM 300
#define KP1 384           // input dim padded to multiple of 128
#define HDIM 1024
#define G4 4096
#define BH (BSZ*HDIM)     // 524288

typedef __attribute__((ext_vector_type(8))) short bf16x8;
typedef __attribute__((ext_vector_type(4))) float f32x4;
typedef __attribute__((ext_vector_type(2))) float f32x2;
typedef __attribute__((ext_vector_type(8))) unsigned short u16x8;
typedef __attribute__((ext_vector_type(4))) unsigned short u16x4;

__device__ __forceinline__ float sigmoidf_(float x){ return 1.f/(1.f+__expf(-x)); }
__device__ __forceinline__ float bf2f(unsigned short u){
    union{unsigned int i; float f;} v; v.i = ((unsigned)u)<<16; return v.f;
}
__device__ __forceinline__ unsigned short f2bf(float f){
    __hip_bfloat16 b = __float2bfloat16(f);
    return *(unsigned short*)&b;
}
// OCP fp8 e4m3 pack/unpack (gfx950 HW convert)
__device__ __forceinline__ unsigned int pack4_fp8(float a, float b, float c2, float d){
    int v = 0;
    v = __builtin_amdgcn_cvt_pk_fp8_f32(a, b, v, false);   // bytes 0,1
    v = __builtin_amdgcn_cvt_pk_fp8_f32(c2, d, v, true);   // bytes 2,3
    return (unsigned int)v;
}
__device__ __forceinline__ void unpack4_fp8(unsigned int v, float* o){
    f32x2 lo = __builtin_amdgcn_cvt_pk_f32_fp8((int)v, false);
    f32x2 hi = __builtin_amdgcn_cvt_pk_f32_fp8((int)v, true);
    o[0]=lo[0]; o[1]=lo[1]; o[2]=hi[0]; o[3]=hi[1];
}

// ---------------- setup kernels ----------------
__global__ void embed_gather_k(const int* __restrict__ x, const float* __restrict__ embed,
                               __hip_bfloat16* __restrict__ xs){
    int t = blockIdx.x, b = blockIdx.y;
    int ix = x[b*SEQ + t];
    const float* src = embed + (size_t)ix * IDIM;
    __hip_bfloat16* dst = xs + ((size_t)t*BSZ + b) * KP1;
    for (int k = threadIdx.x; k < KP1; k += 64)
        dst[k] = __float2bfloat16(k < IDIM ? src[k] : 0.f);
}

// Repack weights to bf16, gate-interleaved rows:
// new row nr -> orig row ((nr>>5)&3)*1024 + (nr>>7)*32 + (nr&31)
__global__ void conv_w_k(const float* __restrict__ Wih_e, const float* __restrict__ Wih_d,
                         const float* __restrict__ Whh_e, const float* __restrict__ Whh_d,
                         __hip_bfloat16* __restrict__ Pe, __hip_bfloat16* __restrict__ Pd,
                         __hip_bfloat16* __restrict__ He, __hip_bfloat16* __restrict__ Hd){
    int nr = blockIdx.x, v = blockIdx.y;
    int orig = ((nr>>5)&3)*HDIM + (nr>>7)*32 + (nr&31);
    if (v < 2){
        const float* src = (v ? Wih_d : Wih_e) + (size_t)orig*IDIM;
        __hip_bfloat16* dst = (v ? Pd : Pe) + (size_t)nr*KP1;
        for (int k = threadIdx.x; k < KP1; k += 64)
            dst[k] = __float2bfloat16(k < IDIM ? src[k] : 0.f);
    } else {
        const float* src = ((v == 3) ? Whh_d : Whh_e) + (size_t)orig*HDIM;
        __hip_bfloat16* dst = ((v == 3) ? Hd : He) + (size_t)nr*HDIM;
        for (int k = threadIdx.x; k < HDIM; k += 64)
            dst[k] = __float2bfloat16(src[k]);
    }
}

__global__ void bias_comb_k(const float* __restrict__ a, const float* __restrict__ b2,
                            const float* __restrict__ c2, const float* __restrict__ d2,
                            float* __restrict__ be, float* __restrict__ bd){
    int i = blockIdx.x*256 + threadIdx.x;       // 8192
    int nr = i & 4095;
    int orig = ((nr>>5)&3)*HDIM + (nr>>7)*32 + (nr&31);
    if (i < G4) be[nr] = a[orig] + b2[orig];
    else        bd[nr] = c2[orig] + d2[orig];
}

__global__ void zero_hc_k(float* __restrict__ h, float* __restrict__ c,
                          __hip_bfloat16* __restrict__ h_bf){
    int idx = blockIdx.x*256 + threadIdx.x;
    h[idx] = 0.f; c[idx] = 0.f; h_bf[idx] = __float2bfloat16(0.f);
}

#define BM 64
#define BN 128
#define NK1 (KP1/128)     // 3
#define NK2 (HDIM/128)    // 8
#define NKT (NK1+NK2)     // 11

// ---------------- fused bf16 MFMA GEMM + LSTM cell (BK=128, 8 waves) ----------------
// mode 0: enc fwd write (fp8, skip h-f32)   mode 1: enc bwd combine (fp8, skip h-f32)
// mode 3: enc bwd LAST (combine + h f32)    mode 2: decoder (h f32, no enc)
__global__ __launch_bounds__(512) void lstm_step_k(
    const __hip_bfloat16* __restrict__ A1, const __hip_bfloat16* __restrict__ B1,
    const __hip_bfloat16* __restrict__ A2, const __hip_bfloat16* __restrict__ B2,
    const float* __restrict__ bias,
    float* __restrict__ c, float* __restrict__ h, __hip_bfloat16* __restrict__ h_bf,
    unsigned char* __restrict__ encSlot, int mode)
{
    __shared__ __align__(16) char smem[98304];
    const int tid  = threadIdx.x;
    const int lane = tid & 63, wv = tid >> 6;
    const int row0 = blockIdx.y * BM;
    const int col0 = blockIdx.x * BN;
    const int wm = wv >> 2, wn = wv & 3;

    f32x4 acc[2][2] = {};

    auto stage = [&](int ks, int p){
        const __hip_bfloat16* A; const __hip_bfloat16* B; int KA, k0;
        if (ks < NK1){ A = A1; B = B1; KA = KP1;  k0 = ks*128; }
        else         { A = A2; B = B2; KA = HDIM; k0 = (ks-NK1)*128; }
        char* base = smem + p*49152;
        #pragma unroll
        for (int half = 0; half < 2; ++half){   // A tile: 1024 slots of 16B, 2 per thread
            int u = half*512 + tid;
            int r = u >> 4, s = u & 15;
            int g = s ^ (r & 15);               // inverse swizzle on global source
            const __hip_bfloat16* src = A + (size_t)(row0 + r)*KA + k0 + g*8;
            char* dst = base + half*8192 + wv*1024;
            __builtin_amdgcn_global_load_lds(
                (const __attribute__((address_space(1))) void*)src,
                (__attribute__((address_space(3))) void*)dst, 16, 0, 0);
        }
        #pragma unroll
        for (int q = 0; q < 4; ++q){            // B tile: 2048 slots, 4 per thread
            int u = q*512 + tid;
            int r = u >> 4, s = u & 15;
            int g = s ^ (r & 15);
            const __hip_bfloat16* src = B + (size_t)(col0 + r)*KA + k0 + g*8;
            char* dst = base + 16384 + q*8192 + wv*1024;
            __builtin_amdgcn_global_load_lds(
                (const __attribute__((address_space(1))) void*)src,
                (__attribute__((address_space(3))) void*)dst, 16, 0, 0);
        }
    };

    auto compute = [&](int p){
        const char* Ab = smem + p*49152;
        const char* Bb = Ab + 16384;
        const int rr = lane & 15, g = lane >> 4;
        bf16x8 af[2][4], bfr[2][4];
        #pragma unroll
        for (int m = 0; m < 2; ++m){
            int r = wm*32 + m*16 + rr;
            #pragma unroll
            for (int kk = 0; kk < 4; ++kk)
                af[m][kk] = *(const bf16x8*)(Ab + r*256 + ((kk*4 + g) ^ (r & 15))*16);
        }
        #pragma unroll
        for (int n = 0; n < 2; ++n){
            int r = wn*32 + n*16 + rr;
            #pragma unroll
            for (int kk = 0; kk < 4; ++kk)
                bfr[n][kk] = *(const bf16x8*)(Bb + r*256 + ((kk*4 + g) ^ (r & 15))*16);
        }
        #pragma unroll
        for (int kk = 0; kk < 4; ++kk)
            #pragma unroll
            for (int m = 0; m < 2; ++m)
                #pragma unroll
                for (int n = 0; n < 2; ++n)
                    acc[m][n] = __builtin_amdgcn_mfma_f32_16x16x32_bf16(af[m][kk], bfr[n][kk], acc[m][n], 0, 0, 0);
    };

    // epilogue indices + c prefetch (latency hides under the K loop)
    const int erow = tid >> 3;
    const int ejj0 = (tid & 7) * 4;
    const size_t ebase = (size_t)(row0 + erow)*HDIM + blockIdx.x*32 + ejj0;

    stage(0, 0);
    const f32x4 cpre = *(const f32x4*)(c + ebase);
    __syncthreads();
    for (int ks = 0; ks < NKT; ++ks){
        int p = ks & 1;
        if (ks + 1 < NKT) stage(ks + 1, p ^ 1);
        compute(p);
        __syncthreads();
    }

    // ---- epilogue: exchange gates via LDS, apply LSTM cell ----
    float* ep = (float*)smem;                    // [gate][64][33] floats
    {
        const int rr = lane & 15, q4 = lane >> 4;
        #pragma unroll
        for (int m = 0; m < 2; ++m){
            int row = wm*32 + m*16 + q4*4;
            #pragma unroll
            for (int n = 0; n < 2; ++n){
                int jj = n*16 + rr;
                float bi = bias[col0 + wn*32 + jj];
                #pragma unroll
                for (int q = 0; q < 4; ++q)
                    ep[(wn*64 + row + q)*33 + jj] = acc[m][n][q] + bi;
            }
        }
    }
    __syncthreads();
    {
        f32x4 cv, hv;
        #pragma unroll
        for (int e = 0; e < 4; ++e){
            float gi = ep[(0*64 + erow)*33 + ejj0 + e];
            float gf = ep[(1*64 + erow)*33 + ejj0 + e];
            float gg = ep[(2*64 + erow)*33 + ejj0 + e];
            float go = ep[(3*64 + erow)*33 + ejj0 + e];
            float cc = sigmoidf_(gf)*cpre[e] + sigmoidf_(gi)*tanhf(gg);
            float hh = sigmoidf_(go)*tanhf(cc);
            cv[e] = cc; hv[e] = hh;
        }
        *(f32x4*)(c + ebase) = cv;
        if (mode >= 2)                           // h f32 live only for decoder / last-enc step
            *(f32x4*)(h + ebase) = hv;
        u16x4 hb;
        #pragma unroll
        for (int e = 0; e < 4; ++e) hb[e] = f2bf(hv[e]);
        *(u16x4*)(h_bf + ebase) = hb;
        if (mode == 0){
            *(unsigned int*)(encSlot + ebase) = pack4_fp8(hv[0], hv[1], hv[2], hv[3]);
        } else if (mode == 1 || mode == 3){
            float eo[4];
            unpack4_fp8(*(const unsigned int*)(encSlot + ebase), eo);
            *(unsigned int*)(encSlot + ebase) =
                pack4_fp8(0.5f*(eo[0]+hv[0]), 0.5f*(eo[1]+hv[1]),
                          0.5f*(eo[2]+hv[2]), 0.5f*(eo[3]+hv[3]));
        }
    }
}

// ---------------- attention logits (+ fused dec_linear of previous step) ----------------
// 1D grid of 640 blocks: bid<512 -> logits (ch = bid&63, 8 timesteps each, h reg-cached);
// bid>=512 -> dec_linear for step dect (4 batches/block).
__global__ __launch_bounds__(256) void attn_part_k(
    const __hip_bfloat16* __restrict__ h_bf, const unsigned char* __restrict__ enc,
    float* __restrict__ part,
    const float* __restrict__ h, const float* __restrict__ Wl, const float* __restrict__ bl,
    const int* __restrict__ len, float* __restrict__ out, int dect)
{
    int lane = threadIdx.x & 63, w = threadIdx.x >> 6;
    if (blockIdx.x < 512){
        int ch = blockIdx.x & 63;                // chunk of 8192 elems
        int s0 = (blockIdx.x >> 6) * 8;          // 8 timesteps per block
        const u16x8* hp = (const u16x8*)(h_bf + (size_t)ch*8192);
        float hf[4][8];
        #pragma unroll
        for (int k = 0; k < 4; ++k){
            u16x8 hv = hp[threadIdx.x + k*256];
            #pragma unroll
            for (int j = 0; j < 8; ++j) hf[k][j] = bf2f(hv[j]);
        }
        __shared__ float red[8][4];
        for (int si = 0; si < 8; ++si){
            const uint2* e = (const uint2*)(enc + (size_t)(s0 + si)*BH + (size_t)ch*8192);
            float sum = 0.f;
            #pragma unroll
            for (int k = 0; k < 4; ++k){
                uint2 ev = e[threadIdx.x + k*256];
                float ef[8];
                unpack4_fp8(ev.x, ef);
                unpack4_fp8(ev.y, ef + 4);
                #pragma unroll
                for (int j = 0; j < 8; ++j) sum += hf[k][j] * ef[j];
            }
            #pragma unroll
            for (int m = 32; m >= 1; m >>= 1) sum += __shfl_xor(sum, m);
            if (lane == 0) red[si][w] = sum;
        }
        __syncthreads();
        if (threadIdx.x < 8){
            int si = threadIdx.x;
            part[(s0 + si)*64 + ch] = red[si][0]+red[si][1]+red[si][2]+red[si][3];
        }
    } else if (dect >= 0){
        int b = (blockIdx.x - 512)*4 + w;       // [0,512)
        const float* hb = h + (size_t)b*HDIM;
        float s0 = 0.f, s1 = 0.f;
        for (int j = lane; j < HDIM; j += 64){
            float v = hb[j];
            s0 += v * Wl[j];
            s1 += v * Wl[HDIM + j];
        }
        #pragma unroll
        for (int m = 32; m >= 1; m >>= 1){ s0 += __shfl_xor(s0, m); s1 += __shfl_xor(s1, m); }
        if (lane == 0){
            bool valid = dect < len[b];
            size_t r = ((size_t)b*SEQ + dect)*2;
            out[r]   = valid ? (s0 + bl[0]) : 1.0f;
            out[r+1] = valid ? (s1 + bl[1]) : 0.0f;
        }
    }
}

// softmax fused; hat written as bf16 (decoder GEMM A2 input). 512 blocks, 4 elems/thread.
__global__ __launch_bounds__(256) void attn_apply_k(
    const float* __restrict__ h, const float* __restrict__ part,
    const unsigned char* __restrict__ enc, __hip_bfloat16* __restrict__ hat_bf)
{
    __shared__ float wl[64];
    int lane = threadIdx.x & 63;
    if (threadIdx.x < 64){
        float tot = 0.f;
        #pragma unroll 8
        for (int ch = 0; ch < 64; ++ch) tot += part[lane*64 + ch];
        float m = tot;
        #pragma unroll
        for (int msk = 32; msk >= 1; msk >>= 1) m = fmaxf(m, __shfl_xor(m, msk));
        float e = __expf(tot - m);
        float sm = e;
        #pragma unroll
        for (int msk = 32; msk >= 1; msk >>= 1) sm += __shfl_xor(sm, msk);
        wl[lane] = e / sm;
    }
    __syncthreads();
    size_t i4 = ((size_t)blockIdx.x*256 + threadIdx.x) * 4;
    float v[4];
    {
        f32x4 a = *(const f32x4*)(h + i4);
        v[0]=a[0]; v[1]=a[1]; v[2]=a[2]; v[3]=a[3];
    }
    for (int s = 0; s < SEQ; ++s){
        unsigned int ev = *(const unsigned int*)(enc + (size_t)s*BH + i4);
        float ef[4];
        unpack4_fp8(ev, ef);
        float ww = wl[s];
        #pragma unroll
        for (int j = 0; j < 4; ++j) v[j] += ww * ef[j];
    }
    u16x4 ov;
    #pragma unroll
    for (int j = 0; j < 4; ++j) ov[j] = f2bf(v[j]);
    *(u16x4*)(hat_bf + i4) = ov;
}

// ---------------- standalone final linear (last decoder step) ----------------
__global__ void dec_linear_k(const float* __restrict__ h, const float* __restrict__ Wl,
                             const float* __restrict__ bl, const int* __restrict__ len,
                             float* __restrict__ out, int t)
{
    int b = blockIdx.x, lane = threadIdx.x;
    const float* hb = h + (size_t)b*HDIM;
    float s0 = 0.f, s1 = 0.f;
    for (int j = lane; j < HDIM; j += 64){
        float v = hb[j];
        s0 += v * Wl[j];
        s1 += v * Wl[HDIM + j];
    }
    #pragma unroll
    for (int m = 32; m >= 1; m >>= 1){ s0 += __shfl_xor(s0, m); s1 += __shfl_xor(s1, m); }
    if (lane == 0){
        bool valid = t < len[b];
        size_t r = ((size_t)b*SEQ + t)*2;
        out[r]   = valid ? (s0 + bl[0]) : 1.0f;
        out[r+1] = valid ? (s1 + bl[1]) : 0.0f;
    }
}

// ---------------- launch ----------------
extern "C" void kernel_launch(void* const* d_in, const int* in_sizes, int n_in,
                              void* d_out, int out_size, void* d_ws, size_t ws_size,
                              hipStream_t stream)
{
    (void)in_sizes; (void)n_in; (void)out_size; (void)ws_size;
    const int*   x      = (const int*)  d_in[0];
    const int*   len    = (const int*)  d_in[1];
    const float* embed  = (const float*)d_in[2];
    const float* Wih_e  = (const float*)d_in[3];
    const float* Whh_e  = (const float*)d_in[4];
    const float* bih_e  = (const float*)d_in[5];
    const float* bhh_e  = (const float*)d_in[6];
    const float* Wih_d  = (const float*)d_in[7];
    const float* Whh_d  = (const float*)d_in[8];
    const float* bih_d  = (const float*)d_in[9];
    const float* bhh_d  = (const float*)d_in[10];
    const float* W_lin  = (const float*)d_in[11];
    const float* b_lin  = (const float*)d_in[12];
    float* out = (float*)d_out;

    float* ws = (float*)d_ws;
    size_t off = 0;
    auto alloc = [&](size_t nfloats){ size_t o = off; off += (nfloats + 63) & ~(size_t)63; return o; };
    __hip_bfloat16* xs_bf  = (__hip_bfloat16*)(ws + alloc((size_t)SEQ*BSZ*KP1/2));
    __hip_bfloat16* Pe     = (__hip_bfloat16*)(ws + alloc((size_t)G4*KP1/2));
    __hip_bfloat16* Pd     = (__hip_bfloat16*)(ws + alloc((size_t)G4*KP1/2));
    __hip_bfloat16* He     = (__hip_bfloat16*)(ws + alloc((size_t)G4*HDIM/2));
    __hip_bfloat16* Hd     = (__hip_bfloat16*)(ws + alloc((size_t)G4*HDIM/2));
    float* be   = ws + alloc(G4);
    float* bd   = ws + alloc(G4);
    float* h    = ws + alloc(BH);
    float* c    = ws + alloc(BH);
    __hip_bfloat16* h_bf   = (__hip_bfloat16*)(ws + alloc(BH/2));
    __hip_bfloat16* hat_bf = (__hip_bfloat16*)(ws + alloc(BH/2));
    unsigned char*  enc    = (unsigned char*)(ws + alloc((size_t)SEQ*BH/4));   // 32 MB fp8
    float* part = ws + alloc(64*64);

    embed_gather_k<<<dim3(SEQ, BSZ), 64, 0, stream>>>(x, embed, xs_bf);
    conv_w_k<<<dim3(G4, 4), 64, 0, stream>>>(Wih_e, Wih_d, Whh_e, Whh_d, Pe, Pd, He, Hd);
    bias_comb_k<<<32, 256, 0, stream>>>(bih_e, bhh_e, bih_d, bhh_d, be, bd);
    zero_hc_k<<<BH/256, 256, 0, stream>>>(h, c, h_bf);

    dim3 ggrid(G4/BN, BSZ/BM);   // (32, 8) = 256 blocks

    // encoder forward (h f32 store skipped — dead)
    for (int t = 0; t < SEQ; ++t)
        lstm_step_k<<<ggrid, 512, 0, stream>>>(xs_bf + (size_t)t*BSZ*KP1, Pe, h_bf, He, be,
                                               c, h, h_bf, enc + (size_t)t*BH, 0);
    // encoder backward (carry continues); combine in place; last step writes h f32 (mode 3)
    for (int k = 0; k < SEQ; ++k){
        int t = SEQ - 1 - k;
        lstm_step_k<<<ggrid, 512, 0, stream>>>(xs_bf + (size_t)t*BSZ*KP1, Pe, h_bf, He, be,
                                               c, h, h_bf, enc + (size_t)k*BH,
                                               (k == SEQ - 1) ? 3 : 1);
    }
    // decoder: attn_part(t) also carries dec_linear(t-1)
    for (int t = 0; t < SEQ; ++t){
        attn_part_k<<<640, 256, 0, stream>>>(h_bf, enc, part, h, W_lin, b_lin, len, out, t - 1);
        attn_apply_k<<<512, 256, 0, stream>>>(h, part, enc, hat_bf);
        lstm_step_k<<<ggrid, 512, 0, stream>>>(xs_bf + (size_t)t*BSZ*KP1, Pd, hat_bf, Hd, bd,
                                               c, h, h_bf, nullptr, 2);
    }
    dec_linear_k<<<BSZ, 64, 0, stream>>>(h, W_lin, b_lin, len, out, SEQ - 1);
}

// Round 20
// 3605.397 us; speedup vs baseline: 3.7676x; 1.0063x over previous
//
#include <hip/hip_runtime.h>
#include <hip/hip_bf16.h>

#define BSZ 512
#define SEQ 64
#define IDIM 300
#define KP1 384           // input dim padded to multiple of 128
#define HDIM 1024
#define G4 4096
#define BH (BSZ*HDIM)     // 524288

typedef __attribute__((ext_vector_type(8))) short bf16x8;
typedef __attribute__((ext_vector_type(4))) float f32x4;
typedef __attribute__((ext_vector_type(2))) float f32x2;
typedef __attribute__((ext_vector_type(8))) unsigned short u16x8;
typedef __attribute__((ext_vector_type(4))) unsigned short u16x4;

__device__ __forceinline__ float sigmoidf_(float x){ return 1.f/(1.f+__expf(-x)); }
__device__ __forceinline__ float bf2f(unsigned short u){
    union{unsigned int i; float f;} v; v.i = ((unsigned)u)<<16; return v.f;
}
__device__ __forceinline__ unsigned short f2bf(float f){
    __hip_bfloat16 b = __float2bfloat16(f);
    return *(unsigned short*)&b;
}
// OCP fp8 e4m3 pack/unpack (gfx950 HW convert)
__device__ __forceinline__ unsigned int pack4_fp8(float a, float b, float c2, float d){
    int v = 0;
    v = __builtin_amdgcn_cvt_pk_fp8_f32(a, b, v, false);   // bytes 0,1
    v = __builtin_amdgcn_cvt_pk_fp8_f32(c2, d, v, true);   // bytes 2,3
    return (unsigned int)v;
}
__device__ __forceinline__ void unpack4_fp8(unsigned int v, float* o){
    f32x2 lo = __builtin_amdgcn_cvt_pk_f32_fp8((int)v, false);
    f32x2 hi = __builtin_amdgcn_cvt_pk_f32_fp8((int)v, true);
    o[0]=lo[0]; o[1]=lo[1]; o[2]=hi[0]; o[3]=hi[1];
}

// ---------------- setup kernels ----------------
__global__ void embed_gather_k(const int* __restrict__ x, const float* __restrict__ embed,
                               __hip_bfloat16* __restrict__ xs){
    int t = blockIdx.x, b = blockIdx.y;
    int ix = x[b*SEQ + t];
    const float* src = embed + (size_t)ix * IDIM;
    __hip_bfloat16* dst = xs + ((size_t)t*BSZ + b) * KP1;
    for (int k = threadIdx.x; k < KP1; k += 64)
        dst[k] = __float2bfloat16(k < IDIM ? src[k] : 0.f);
}

// Repack weights to bf16, gate-interleaved rows:
// new row nr -> orig row ((nr>>5)&3)*1024 + (nr>>7)*32 + (nr&31)
__global__ void conv_w_k(const float* __restrict__ Wih_e, const float* __restrict__ Wih_d,
                         const float* __restrict__ Whh_e, const float* __restrict__ Whh_d,
                         __hip_bfloat16* __restrict__ Pe, __hip_bfloat16* __restrict__ Pd,
                         __hip_bfloat16* __restrict__ He, __hip_bfloat16* __restrict__ Hd){
    int nr = blockIdx.x, v = blockIdx.y;
    int orig = ((nr>>5)&3)*HDIM + (nr>>7)*32 + (nr&31);
    if (v < 2){
        const float* src = (v ? Wih_d : Wih_e) + (size_t)orig*IDIM;
        __hip_bfloat16* dst = (v ? Pd : Pe) + (size_t)nr*KP1;
        for (int k = threadIdx.x; k < KP1; k += 64)
            dst[k] = __float2bfloat16(k < IDIM ? src[k] : 0.f);
    } else {
        const float* src = ((v == 3) ? Whh_d : Whh_e) + (size_t)orig*HDIM;
        __hip_bfloat16* dst = ((v == 3) ? Hd : He) + (size_t)nr*HDIM;
        for (int k = threadIdx.x; k < HDIM; k += 64)
            dst[k] = __float2bfloat16(src[k]);
    }
}

__global__ void bias_comb_k(const float* __restrict__ a, const float* __restrict__ b2,
                            const float* __restrict__ c2, const float* __restrict__ d2,
                            float* __restrict__ be, float* __restrict__ bd){
    int i = blockIdx.x*256 + threadIdx.x;       // 8192
    int nr = i & 4095;
    int orig = ((nr>>5)&3)*HDIM + (nr>>7)*32 + (nr&31);
    if (i < G4) be[nr] = a[orig] + b2[orig];
    else        bd[nr] = c2[orig] + d2[orig];
}

__global__ void zero_hc_k(float* __restrict__ h, float* __restrict__ c,
                          __hip_bfloat16* __restrict__ h_bf){
    int idx = blockIdx.x*256 + threadIdx.x;
    h[idx] = 0.f; c[idx] = 0.f; h_bf[idx] = __float2bfloat16(0.f);
}

#define BM 64
#define BN 128
#define NK1 (KP1/128)     // 3
#define NK2 (HDIM/128)    // 8
#define NKT (NK1+NK2)     // 11

// ---------------- fused bf16 MFMA GEMM + LSTM cell (BK=128, 8 waves, XCD-grouped) ----------------
// 1D grid 256. xcd = fid&7 owns col-groups 4*xcd..4*xcd+3, so the 8 row-blocks sharing a
// B col-panel land on ONE XCD -> 7 of 8 B-panel stagings become L2 hits.
// mode 0: enc fwd write (fp8, skip h-f32)   mode 1: enc bwd combine (fp8, skip h-f32)
// mode 3: enc bwd LAST (combine + h f32)    mode 2: decoder (h f32, no enc)
__global__ __launch_bounds__(512) void lstm_step_k(
    const __hip_bfloat16* __restrict__ A1, const __hip_bfloat16* __restrict__ B1,
    const __hip_bfloat16* __restrict__ A2, const __hip_bfloat16* __restrict__ B2,
    const float* __restrict__ bias,
    float* __restrict__ c, float* __restrict__ h, __hip_bfloat16* __restrict__ h_bf,
    unsigned char* __restrict__ encSlot, int mode)
{
    __shared__ __align__(16) char smem[98304];
    const int tid  = threadIdx.x;
    const int lane = tid & 63, wv = tid >> 6;
    // XCD-grouped mapping (R5 pattern, bit-identical math)
    const int fid = blockIdx.x;                  // [0,256)
    const int xcd = fid & 7, ii = fid >> 3;      // ii in [0,32)
    const int cg   = xcd*4 + (ii & 3);           // col group 0..31
    const int rowg = ii >> 2;                    // row group 0..7
    const int row0 = rowg * BM;
    const int col0 = cg * BN;
    const int wm = wv >> 2, wn = wv & 3;

    f32x4 acc[2][2] = {};

    auto stage = [&](int ks, int p){
        const __hip_bfloat16* A; const __hip_bfloat16* B; int KA, k0;
        if (ks < NK1){ A = A1; B = B1; KA = KP1;  k0 = ks*128; }
        else         { A = A2; B = B2; KA = HDIM; k0 = (ks-NK1)*128; }
        char* base = smem + p*49152;
        #pragma unroll
        for (int half = 0; half < 2; ++half){   // A tile: 1024 slots of 16B, 2 per thread
            int u = half*512 + tid;
            int r = u >> 4, s = u & 15;
            int g = s ^ (r & 15);               // inverse swizzle on global source
            const __hip_bfloat16* src = A + (size_t)(row0 + r)*KA + k0 + g*8;
            char* dst = base + half*8192 + wv*1024;
            __builtin_amdgcn_global_load_lds(
                (const __attribute__((address_space(1))) void*)src,
                (__attribute__((address_space(3))) void*)dst, 16, 0, 0);
        }
        #pragma unroll
        for (int q = 0; q < 4; ++q){            // B tile: 2048 slots, 4 per thread
            int u = q*512 + tid;
            int r = u >> 4, s = u & 15;
            int g = s ^ (r & 15);
            const __hip_bfloat16* src = B + (size_t)(col0 + r)*KA + k0 + g*8;
            char* dst = base + 16384 + q*8192 + wv*1024;
            __builtin_amdgcn_global_load_lds(
                (const __attribute__((address_space(1))) void*)src,
                (__attribute__((address_space(3))) void*)dst, 16, 0, 0);
        }
    };

    auto compute = [&](int p){
        const char* Ab = smem + p*49152;
        const char* Bb = Ab + 16384;
        const int rr = lane & 15, g = lane >> 4;
        bf16x8 af[2][4], bfr[2][4];
        #pragma unroll
        for (int m = 0; m < 2; ++m){
            int r = wm*32 + m*16 + rr;
            #pragma unroll
            for (int kk = 0; kk < 4; ++kk)
                af[m][kk] = *(const bf16x8*)(Ab + r*256 + ((kk*4 + g) ^ (r & 15))*16);
        }
        #pragma unroll
        for (int n = 0; n < 2; ++n){
            int r = wn*32 + n*16 + rr;
            #pragma unroll
            for (int kk = 0; kk < 4; ++kk)
                bfr[n][kk] = *(const bf16x8*)(Bb + r*256 + ((kk*4 + g) ^ (r & 15))*16);
        }
        #pragma unroll
        for (int kk = 0; kk < 4; ++kk)
            #pragma unroll
            for (int m = 0; m < 2; ++m)
                #pragma unroll
                for (int n = 0; n < 2; ++n)
                    acc[m][n] = __builtin_amdgcn_mfma_f32_16x16x32_bf16(af[m][kk], bfr[n][kk], acc[m][n], 0, 0, 0);
    };

    // epilogue indices + c prefetch (latency hides under the K loop)
    const int erow = tid >> 3;
    const int ejj0 = (tid & 7) * 4;
    const size_t ebase = (size_t)(row0 + erow)*HDIM + cg*32 + ejj0;

    stage(0, 0);
    const f32x4 cpre = *(const f32x4*)(c + ebase);
    __syncthreads();
    for (int ks = 0; ks < NKT; ++ks){
        int p = ks & 1;
        if (ks + 1 < NKT) stage(ks + 1, p ^ 1);
        compute(p);
        __syncthreads();
    }

    // ---- epilogue: exchange gates via LDS, apply LSTM cell ----
    float* ep = (float*)smem;                    // [gate][64][33] floats
    {
        const int rr = lane & 15, q4 = lane >> 4;
        #pragma unroll
        for (int m = 0; m < 2; ++m){
            int row = wm*32 + m*16 + q4*4;
            #pragma unroll
            for (int n = 0; n < 2; ++n){
                int jj = n*16 + rr;
                float bi = bias[col0 + wn*32 + jj];
                #pragma unroll
                for (int q = 0; q < 4; ++q)
                    ep[(wn*64 + row + q)*33 + jj] = acc[m][n][q] + bi;
            }
        }
    }
    __syncthreads();
    {
        f32x4 cv, hv;
        #pragma unroll
        for (int e = 0; e < 4; ++e){
            float gi = ep[(0*64 + erow)*33 + ejj0 + e];
            float gf = ep[(1*64 + erow)*33 + ejj0 + e];
            float gg = ep[(2*64 + erow)*33 + ejj0 + e];
            float go = ep[(3*64 + erow)*33 + ejj0 + e];
            float cc = sigmoidf_(gf)*cpre[e] + sigmoidf_(gi)*tanhf(gg);
            float hh = sigmoidf_(go)*tanhf(cc);
            cv[e] = cc; hv[e] = hh;
        }
        *(f32x4*)(c + ebase) = cv;
        if (mode >= 2)                           // h f32 live only for decoder / last-enc step
            *(f32x4*)(h + ebase) = hv;
        u16x4 hb;
        #pragma unroll
        for (int e = 0; e < 4; ++e) hb[e] = f2bf(hv[e]);
        *(u16x4*)(h_bf + ebase) = hb;
        if (mode == 0){
            *(unsigned int*)(encSlot + ebase) = pack4_fp8(hv[0], hv[1], hv[2], hv[3]);
        } else if (mode == 1 || mode == 3){
            float eo[4];
            unpack4_fp8(*(const unsigned int*)(encSlot + ebase), eo);
            *(unsigned int*)(encSlot + ebase) =
                pack4_fp8(0.5f*(eo[0]+hv[0]), 0.5f*(eo[1]+hv[1]),
                          0.5f*(eo[2]+hv[2]), 0.5f*(eo[3]+hv[3]));
        }
    }
}

// ---------------- attention logits (+ fused dec_linear of previous step) ----------------
// 1D grid of 640 blocks: bid<512 -> logits (ch = bid&63, 8 timesteps each, h reg-cached);
// bid>=512 -> dec_linear for step dect (4 batches/block).
__global__ __launch_bounds__(256) void attn_part_k(
    const __hip_bfloat16* __restrict__ h_bf, const unsigned char* __restrict__ enc,
    float* __restrict__ part,
    const float* __restrict__ h, const float* __restrict__ Wl, const float* __restrict__ bl,
    const int* __restrict__ len, float* __restrict__ out, int dect)
{
    int lane = threadIdx.x & 63, w = threadIdx.x >> 6;
    if (blockIdx.x < 512){
        int ch = blockIdx.x & 63;                // chunk of 8192 elems
        int s0 = (blockIdx.x >> 6) * 8;          // 8 timesteps per block
        const u16x8* hp = (const u16x8*)(h_bf + (size_t)ch*8192);
        float hf[4][8];
        #pragma unroll
        for (int k = 0; k < 4; ++k){
            u16x8 hv = hp[threadIdx.x + k*256];
            #pragma unroll
            for (int j = 0; j < 8; ++j) hf[k][j] = bf2f(hv[j]);
        }
        __shared__ float red[8][4];
        for (int si = 0; si < 8; ++si){
            const uint2* e = (const uint2*)(enc + (size_t)(s0 + si)*BH + (size_t)ch*8192);
            float sum = 0.f;
            #pragma unroll
            for (int k = 0; k < 4; ++k){
                uint2 ev = e[threadIdx.x + k*256];
                float ef[8];
                unpack4_fp8(ev.x, ef);
                unpack4_fp8(ev.y, ef + 4);
                #pragma unroll
                for (int j = 0; j < 8; ++j) sum += hf[k][j] * ef[j];
            }
            #pragma unroll
            for (int m = 32; m >= 1; m >>= 1) sum += __shfl_xor(sum, m);
            if (lane == 0) red[si][w] = sum;
        }
        __syncthreads();
        if (threadIdx.x < 8){
            int si = threadIdx.x;
            part[(s0 + si)*64 + ch] = red[si][0]+red[si][1]+red[si][2]+red[si][3];
        }
    } else if (dect >= 0){
        int b = (blockIdx.x - 512)*4 + w;       // [0,512)
        const float* hb = h + (size_t)b*HDIM;
        float s0 = 0.f, s1 = 0.f;
        for (int j = lane; j < HDIM; j += 64){
            float v = hb[j];
            s0 += v * Wl[j];
            s1 += v * Wl[HDIM + j];
        }
        #pragma unroll
        for (int m = 32; m >= 1; m >>= 1){ s0 += __shfl_xor(s0, m); s1 += __shfl_xor(s1, m); }
        if (lane == 0){
            bool valid = dect < len[b];
            size_t r = ((size_t)b*SEQ + dect)*2;
            out[r]   = valid ? (s0 + bl[0]) : 1.0f;
            out[r+1] = valid ? (s1 + bl[1]) : 0.0f;
        }
    }
}

// softmax fused; hat written as bf16 (decoder GEMM A2 input). 512 blocks, 4 elems/thread.
__global__ __launch_bounds__(256) void attn_apply_k(
    const float* __restrict__ h, const float* __restrict__ part,
    const unsigned char* __restrict__ enc, __hip_bfloat16* __restrict__ hat_bf)
{
    __shared__ float wl[64];
    int lane = threadIdx.x & 63;
    if (threadIdx.x < 64){
        float tot = 0.f;
        #pragma unroll 8
        for (int ch = 0; ch < 64; ++ch) tot += part[lane*64 + ch];
        float m = tot;
        #pragma unroll
        for (int msk = 32; msk >= 1; msk >>= 1) m = fmaxf(m, __shfl_xor(m, msk));
        float e = __expf(tot - m);
        float sm = e;
        #pragma unroll
        for (int msk = 32; msk >= 1; msk >>= 1) sm += __shfl_xor(sm, msk);
        wl[lane] = e / sm;
    }
    __syncthreads();
    size_t i4 = ((size_t)blockIdx.x*256 + threadIdx.x) * 4;
    float v[4];
    {
        f32x4 a = *(const f32x4*)(h + i4);
        v[0]=a[0]; v[1]=a[1]; v[2]=a[2]; v[3]=a[3];
    }
    for (int s = 0; s < SEQ; ++s){
        unsigned int ev = *(const unsigned int*)(enc + (size_t)s*BH + i4);
        float ef[4];
        unpack4_fp8(ev, ef);
        float ww = wl[s];
        #pragma unroll
        for (int j = 0; j < 4; ++j) v[j] += ww * ef[j];
    }
    u16x4 ov;
    #pragma unroll
    for (int j = 0; j < 4; ++j) ov[j] = f2bf(v[j]);
    *(u16x4*)(hat_bf + i4) = ov;
}

// ---------------- standalone final linear (last decoder step) ----------------
__global__ void dec_linear_k(const float* __restrict__ h, const float* __restrict__ Wl,
                             const float* __restrict__ bl, const int* __restrict__ len,
                             float* __restrict__ out, int t)
{
    int b = blockIdx.x, lane = threadIdx.x;
    const float* hb = h + (size_t)b*HDIM;
    float s0 = 0.f, s1 = 0.f;
    for (int j = lane; j < HDIM; j += 64){
        float v = hb[j];
        s0 += v * Wl[j];
        s1 += v * Wl[HDIM + j];
    }
    #pragma unroll
    for (int m = 32; m >= 1; m >>= 1){ s0 += __shfl_xor(s0, m); s1 += __shfl_xor(s1, m); }
    if (lane == 0){
        bool valid = t < len[b];
        size_t r = ((size_t)b*SEQ + t)*2;
        out[r]   = valid ? (s0 + bl[0]) : 1.0f;
        out[r+1] = valid ? (s1 + bl[1]) : 0.0f;
    }
}

// ---------------- launch ----------------
extern "C" void kernel_launch(void* const* d_in, const int* in_sizes, int n_in,
                              void* d_out, int out_size, void* d_ws, size_t ws_size,
                              hipStream_t stream)
{
    (void)in_sizes; (void)n_in; (void)out_size; (void)ws_size;
    const int*   x      = (const int*)  d_in[0];
    const int*   len    = (const int*)  d_in[1];
    const float* embed  = (const float*)d_in[2];
    const float* Wih_e  = (const float*)d_in[3];
    const float* Whh_e  = (const float*)d_in[4];
    const float* bih_e  = (const float*)d_in[5];
    const float* bhh_e  = (const float*)d_in[6];
    const float* Wih_d  = (const float*)d_in[7];
    const float* Whh_d  = (const float*)d_in[8];
    const float* bih_d  = (const float*)d_in[9];
    const float* bhh_d  = (const float*)d_in[10];
    const float* W_lin  = (const float*)d_in[11];
    const float* b_lin  = (const float*)d_in[12];
    float* out = (float*)d_out;

    float* ws = (float*)d_ws;
    size_t off = 0;
    auto alloc = [&](size_t nfloats){ size_t o = off; off += (nfloats + 63) & ~(size_t)63; return o; };
    __hip_bfloat16* xs_bf  = (__hip_bfloat16*)(ws + alloc((size_t)SEQ*BSZ*KP1/2));
    __hip_bfloat16* Pe     = (__hip_bfloat16*)(ws + alloc((size_t)G4*KP1/2));
    __hip_bfloat16* Pd     = (__hip_bfloat16*)(ws + alloc((size_t)G4*KP1/2));
    __hip_bfloat16* He     = (__hip_bfloat16*)(ws + alloc((size_t)G4*HDIM/2));
    __hip_bfloat16* Hd     = (__hip_bfloat16*)(ws + alloc((size_t)G4*HDIM/2));
    float* be   = ws + alloc(G4);
    float* bd   = ws + alloc(G4);
    float* h    = ws + alloc(BH);
    float* c    = ws + alloc(BH);
    __hip_bfloat16* h_bf   = (__hip_bfloat16*)(ws + alloc(BH/2));
    __hip_bfloat16* hat_bf = (__hip_bfloat16*)(ws + alloc(BH/2));
    unsigned char*  enc    = (unsigned char*)(ws + alloc((size_t)SEQ*BH/4));   // 32 MB fp8
    float* part = ws + alloc(64*64);

    embed_gather_k<<<dim3(SEQ, BSZ), 64, 0, stream>>>(x, embed, xs_bf);
    conv_w_k<<<dim3(G4, 4), 64, 0, stream>>>(Wih_e, Wih_d, Whh_e, Whh_d, Pe, Pd, He, Hd);
    bias_comb_k<<<32, 256, 0, stream>>>(bih_e, bhh_e, bih_d, bhh_d, be, bd);
    zero_hc_k<<<BH/256, 256, 0, stream>>>(h, c, h_bf);

    // encoder forward (h f32 store skipped — dead)
    for (int t = 0; t < SEQ; ++t)
        lstm_step_k<<<256, 512, 0, stream>>>(xs_bf + (size_t)t*BSZ*KP1, Pe, h_bf, He, be,
                                             c, h, h_bf, enc + (size_t)t*BH, 0);
    // encoder backward (carry continues); combine in place; last step writes h f32 (mode 3)
    for (int k = 0; k < SEQ; ++k){
        int t = SEQ - 1 - k;
        lstm_step_k<<<256, 512, 0, stream>>>(xs_bf + (size_t)t*BSZ*KP1, Pe, h_bf, He, be,
                                             c, h, h_bf, enc + (size_t)k*BH,
                                             (k == SEQ - 1) ? 3 : 1);
    }
    // decoder: attn_part(t) also carries dec_linear(t-1)
    for (int t = 0; t < SEQ; ++t){
        attn_part_k<<<640, 256, 0, stream>>>(h_bf, enc, part, h, W_lin, b_lin, len, out, t - 1);
        attn_apply_k<<<512, 256, 0, stream>>>(h, part, enc, hat_bf);
        lstm_step_k<<<256, 512, 0, stream>>>(xs_bf + (size_t)t*BSZ*KP1, Pd, hat_bf, Hd, bd,
                                             c, h, h_bf, nullptr, 2);
    }
    dec_linear_k<<<BSZ, 64, 0, stream>>>(h, W_lin, b_lin, len, out, SEQ - 1);
}